// Round 2
// baseline (469.420 us; speedup 1.0000x reference)
//
#include <hip/hip_runtime.h>
#include <hip/hip_bf16.h>

#define BS 4
#define SEQ 2048
#define DIM 512
#define HEADS 8
#define HD 64
#define ROWS (BS*SEQ)   // 8192
// logits scaled to exp2 domain: 1/sqrt(64) * log2(e)
#define SCL2E 0.1803368801111244f
#define NEGB (-1.4426950408889634e6f)   // -1e6 * log2(e)

typedef __attribute__((ext_vector_type(8))) short bf16x8;
typedef __attribute__((ext_vector_type(4))) float floatx4;

__device__ __forceinline__ unsigned short f2bf(float f) {
    union { float f; unsigned u; } v; v.f = f;
    unsigned r = v.u + 0x7fff + ((v.u >> 16) & 1);
    return (unsigned short)(r >> 16);
}

__device__ __forceinline__ unsigned pack2bf(float a, float b) {
#if __has_builtin(__builtin_amdgcn_cvt_pk_bf16_f32)
    typedef __attribute__((ext_vector_type(2))) __bf16 bf2;
    union { bf2 v; unsigned u; } cv;
    cv.v = __builtin_amdgcn_cvt_pk_bf16_f32(a, b);
    return cv.u;
#else
    return (unsigned)f2bf(a) | ((unsigned)f2bf(b) << 16);
#endif
}

__device__ __forceinline__ float fexp2(float x) {
#if __has_builtin(__builtin_amdgcn_exp2f)
    return __builtin_amdgcn_exp2f(x);
#else
    return exp2f(x);
#endif
}

// ---------------- fp32 -> bf16 conversion of x, weights; mask -> exp2 bias --
// units of 4 elems. x: 1048576, W: 4*65536, bias: 2048. grid = 5128*256.
__global__ __launch_bounds__(256) void convert_all(
    const float* __restrict__ x, const float* __restrict__ Wq,
    const float* __restrict__ Wk, const float* __restrict__ Wv,
    const float* __restrict__ Wo, const int* __restrict__ mask,
    unsigned short* __restrict__ xb, unsigned short* __restrict__ wqb,
    unsigned short* __restrict__ wkb, unsigned short* __restrict__ wvb,
    unsigned short* __restrict__ wob, float* __restrict__ biasf)
{
    int i = blockIdx.x * 256 + threadIdx.x;
    if (i < 1048576 + 262144) {
        const float* src; unsigned short* dst; int off;
        if (i < 1048576) { src = x; dst = xb; off = i; }
        else {
            int j = i - 1048576; int seg = j >> 16; off = j & 65535;
            src = seg == 0 ? Wq : seg == 1 ? Wk : seg == 2 ? Wv : Wo;
            dst = seg == 0 ? wqb : seg == 1 ? wkb : seg == 2 ? wvb : wob;
        }
        float4 v = ((const float4*)src)[off];
        ushort4 o;
        o.x = f2bf(v.x); o.y = f2bf(v.y); o.z = f2bf(v.z); o.w = f2bf(v.w);
        ((ushort4*)dst)[off] = o;
    } else {
        int jb = i - 1310720;                      // 0..2047
        int4 mv = ((const int4*)mask)[jb];
        float4 bo;
        bo.x = (mv.x == 1) ? 0.f : NEGB;
        bo.y = (mv.y == 1) ? 0.f : NEGB;
        bo.z = (mv.z == 1) ? 0.f : NEGB;
        bo.w = (mv.w == 1) ? 0.f : NEGB;
        ((float4*)biasf)[jb] = bo;
    }
}

// ---------------- QKV projection: C = A @ W^T ------------------------------
// z==0/1 (Q/K): head-split (b,h,n,d) bf16.  z==2 (V): transposed (b,h,d,n).
__global__ __launch_bounds__(256) void gemm_qkv(
    const unsigned short* __restrict__ A,
    const unsigned short* __restrict__ W0, const unsigned short* __restrict__ W1,
    const unsigned short* __restrict__ W2,
    unsigned short* __restrict__ O0, unsigned short* __restrict__ O1,
    unsigned short* __restrict__ O2)
{
    const unsigned short* Bt = blockIdx.z == 0 ? W0 : blockIdx.z == 1 ? W1 : W2;
    int n0 = blockIdx.x * 64;
    int m0 = blockIdx.y * 64;
    int tid = threadIdx.x;
    int w = tid >> 6, lane = tid & 63, quad = lane >> 4, l16 = lane & 15;

    const unsigned short* Ap = A + (long)(m0 + w*16 + l16) * DIM + quad * 8;
    const unsigned short* Bp = Bt + (long)(n0 + l16) * DIM + quad * 8;

    floatx4 acc[4];
    #pragma unroll
    for (int ct = 0; ct < 4; ct++) acc[ct] = (floatx4){0.f, 0.f, 0.f, 0.f};

    for (int k0 = 0; k0 < DIM; k0 += 32) {
        bf16x8 a = *(const bf16x8*)(Ap + k0);
        #pragma unroll
        for (int ct = 0; ct < 4; ct++) {
            bf16x8 b = *(const bf16x8*)(Bp + (long)ct * 16 * DIM + k0);
            acc[ct] = __builtin_amdgcn_mfma_f32_16x16x32_bf16(a, b, acc[ct], 0, 0, 0);
        }
    }
    if (blockIdx.z == 2) {
        // V transposed: Vt[(b*H+h)*64 + d][n], 4 consecutive n per lane -> 8B store
        #pragma unroll
        for (int ct = 0; ct < 4; ct++) {
            int col = n0 + ct*16 + l16;             // h*64 + d
            int h = col >> 6, d = col & 63;
            int rowb = m0 + w*16 + quad*4;          // b*SEQ + n (4 consecutive)
            int b = rowb >> 11, n = rowb & 2047;
            ushort4 st;
            st.x = f2bf(acc[ct][0]); st.y = f2bf(acc[ct][1]);
            st.z = f2bf(acc[ct][2]); st.w = f2bf(acc[ct][3]);
            *(ushort4*)&O2[((long)((b * HEADS + h) * HD + d) << 11) + n] = st;
        }
    } else {
        unsigned short* Out = blockIdx.z == 0 ? O0 : O1;
        #pragma unroll
        for (int ct = 0; ct < 4; ct++) {
            #pragma unroll
            for (int r = 0; r < 4; r++) {
                int row = m0 + w*16 + quad*4 + r;   // b*SEQ + n
                int col = n0 + ct*16 + l16;         // h*64 + d
                int b = row >> 11, n = row & 2047, h = col >> 6, d = col & 63;
                Out[(((long)(b * HEADS + h) * SEQ + n) << 6) + d] = f2bf(acc[ct][r]);
            }
        }
    }
}

// ---------------- flash attention (S^T orientation, no barriers) ------------
// Block: (b, h, 64 q-rows) = 4 waves x 16 q. K tiles of 64 keys.
// S^T = K·Q^T : A=K (direct global), B=Q (regs). C-layout: q=l16, key=quad*4+r.
// P·V: A=P (per-wave LDS round-trip), B=V^T (direct global (b,h,d,seq)).
__global__ __launch_bounds__(256) void flash_attn(
    const unsigned short* __restrict__ Q, const unsigned short* __restrict__ K,
    const unsigned short* __restrict__ Vt, const float* __restrict__ biasf,
    unsigned short* __restrict__ ctx)
{
    __shared__ unsigned short Pt[4][16 * 72];   // per-wave P[q][key], stride 72

    int bx = blockIdx.x;
    int q0 = (bx & 31) * 64;
    int h  = (bx >> 5) & 7;
    int b  = bx >> 8;
    long bh = (long)(b * HEADS + h) * SEQ;

    int tid = threadIdx.x;
    int w = tid >> 6, lane = tid & 63, quad = lane >> 4, l16 = lane & 15;

    // Q B-fragments (n=l16 -> q, k=quad*8+j -> d), live whole kernel
    const unsigned short* Qp = Q + (bh + q0 + w*16 + l16) * HD + quad * 8;
    bf16x8 qb0 = *(const bf16x8*)(Qp);
    bf16x8 qb1 = *(const bf16x8*)(Qp + 32);

    const unsigned short* Kbase = K + (bh + l16) * HD + quad * 8;              // + key*64
    const unsigned short* Vbase = Vt + (((long)(b * HEADS + h) * HD + l16) << 11) + quad * 8; // + (ct*16)*2048 + key
    const float* bbase = biasf + b * SEQ + quad * 4;                           // + kt + nt*16
    unsigned short* Pw = &Pt[w][0];

    floatx4 o[4];
    #pragma unroll
    for (int ct = 0; ct < 4; ct++) o[ct] = (floatx4){0.f, 0.f, 0.f, 0.f};
    float m_i = -1e30f, l_i = 0.f;

    for (int kt = 0; kt < SEQ; kt += 64) {
        // ---- S^T = K.Q^T (scaled to exp2 domain) + mask bias ----
        floatx4 s[4];
        #pragma unroll
        for (int nt = 0; nt < 4; nt++) {
            const unsigned short* kp = Kbase + (long)(kt + nt*16) * HD;
            bf16x8 ka0 = *(const bf16x8*)(kp);
            bf16x8 ka1 = *(const bf16x8*)(kp + 32);
            floatx4 t = (floatx4){0.f, 0.f, 0.f, 0.f};
            t = __builtin_amdgcn_mfma_f32_16x16x32_bf16(ka0, qb0, t, 0, 0, 0);
            t = __builtin_amdgcn_mfma_f32_16x16x32_bf16(ka1, qb1, t, 0, 0, 0);
            float4 bv = *(const float4*)(bbase + kt + nt*16);
            s[nt][0] = fmaf(t[0], SCL2E, bv.x);
            s[nt][1] = fmaf(t[1], SCL2E, bv.y);
            s[nt][2] = fmaf(t[2], SCL2E, bv.z);
            s[nt][3] = fmaf(t[3], SCL2E, bv.w);
        }

        // ---- V B-fragments issued early (consumed after softmax) ----
        bf16x8 vb[4][2];
        #pragma unroll
        for (int ct = 0; ct < 4; ct++) {
            const unsigned short* vp = Vbase + ((long)(ct*16) << 11) + kt;
            vb[ct][0] = *(const bf16x8*)(vp);
            vb[ct][1] = *(const bf16x8*)(vp + 32);
        }

        // ---- online softmax (per-lane q=l16; reduce over quads) ----
        float vmax = s[0][0];
        #pragma unroll
        for (int nt = 0; nt < 4; nt++)
            #pragma unroll
            for (int r = 0; r < 4; r++) vmax = fmaxf(vmax, s[nt][r]);
        vmax = fmaxf(vmax, __shfl_xor(vmax, 16));
        vmax = fmaxf(vmax, __shfl_xor(vmax, 32));
        float mnew = fmaxf(m_i, vmax);
        float alpha = fexp2(m_i - mnew);
        m_i = mnew;

        float p[4][4]; float sum = 0.f;
        #pragma unroll
        for (int nt = 0; nt < 4; nt++)
            #pragma unroll
            for (int r = 0; r < 4; r++) {
                p[nt][r] = fexp2(s[nt][r] - mnew);
                sum += p[nt][r];
            }
        sum += __shfl_xor(sum, 16);
        sum += __shfl_xor(sum, 32);
        l_i = l_i * alpha + sum;

        // alpha redistribution to o-rows (q = quad*4+r lives on lane quad*4+r)
        float a0 = __shfl(alpha, quad*4 + 0);
        float a1 = __shfl(alpha, quad*4 + 1);
        float a2 = __shfl(alpha, quad*4 + 2);
        float a3 = __shfl(alpha, quad*4 + 3);
        #pragma unroll
        for (int ct = 0; ct < 4; ct++) {
            o[ct][0] *= a0; o[ct][1] *= a1; o[ct][2] *= a2; o[ct][3] *= a3;
        }

        // ---- P -> per-wave LDS (q,key layout), packed 8B writes ----
        #pragma unroll
        for (int nt = 0; nt < 4; nt++) {
            uint2 pu;
            pu.x = pack2bf(p[nt][0], p[nt][1]);
            pu.y = pack2bf(p[nt][2], p[nt][3]);
            *(uint2*)&Pw[l16 * 72 + nt*16 + quad*4] = pu;
        }
        // same-wave LDS ordering: compiler inserts lgkmcnt; no barrier needed

        // ---- O += P @ V ----
        #pragma unroll
        for (int g = 0; g < 2; g++) {
            bf16x8 pa = *(const bf16x8*)&Pw[l16 * 72 + g*32 + quad*8];
            #pragma unroll
            for (int ct = 0; ct < 4; ct++)
                o[ct] = __builtin_amdgcn_mfma_f32_16x16x32_bf16(pa, vb[ct][g], o[ct], 0, 0, 0);
        }
    }

    // ---- epilogue: ctx[b*SEQ+q][h*64+d] = O / l ----
    float inv = 1.0f / l_i;                    // per lane, q = l16
    float i0 = __shfl(inv, quad*4 + 0);
    float i1 = __shfl(inv, quad*4 + 1);
    float i2 = __shfl(inv, quad*4 + 2);
    float i3 = __shfl(inv, quad*4 + 3);
    #pragma unroll
    for (int ct = 0; ct < 4; ct++) {
        int col = h * HD + ct*16 + l16;
        long rb = (long)(b * SEQ + q0 + w*16 + quad*4);
        ctx[(rb + 0) * DIM + col] = f2bf(o[ct][0] * i0);
        ctx[(rb + 1) * DIM + col] = f2bf(o[ct][1] * i1);
        ctx[(rb + 2) * DIM + col] = f2bf(o[ct][2] * i2);
        ctx[(rb + 3) * DIM + col] = f2bf(o[ct][3] * i3);
    }
}

// ---------------- output projection: out = ctx @ Wo^T (fp32 out) ------------
__global__ __launch_bounds__(256) void gemm_proj(
    const unsigned short* __restrict__ A, const unsigned short* __restrict__ Bt,
    float* __restrict__ Out)
{
    int n0 = blockIdx.x * 64;
    int m0 = blockIdx.y * 64;
    int tid = threadIdx.x;
    int w = tid >> 6, lane = tid & 63, quad = lane >> 4, l16 = lane & 15;

    const unsigned short* Ap = A + (long)(m0 + w*16 + l16) * DIM + quad * 8;
    const unsigned short* Bp = Bt + (long)(n0 + l16) * DIM + quad * 8;

    floatx4 acc[4];
    #pragma unroll
    for (int ct = 0; ct < 4; ct++) acc[ct] = (floatx4){0.f, 0.f, 0.f, 0.f};

    for (int k0 = 0; k0 < DIM; k0 += 32) {
        bf16x8 a = *(const bf16x8*)(Ap + k0);
        #pragma unroll
        for (int ct = 0; ct < 4; ct++) {
            bf16x8 b = *(const bf16x8*)(Bp + (long)ct * 16 * DIM + k0);
            acc[ct] = __builtin_amdgcn_mfma_f32_16x16x32_bf16(a, b, acc[ct], 0, 0, 0);
        }
    }
    #pragma unroll
    for (int ct = 0; ct < 4; ct++) {
        #pragma unroll
        for (int r = 0; r < 4; r++) {
            int row = m0 + w*16 + quad*4 + r;
            int col = n0 + ct*16 + l16;
            Out[(long)row * DIM + col] = acc[ct][r];
        }
    }
}

extern "C" void kernel_launch(void* const* d_in, const int* in_sizes, int n_in,
                              void* d_out, int out_size, void* d_ws, size_t ws_size,
                              hipStream_t stream) {
    const float* x  = (const float*)d_in[0];
    const float* Wq = (const float*)d_in[1];
    const float* Wk = (const float*)d_in[2];
    const float* Wv = (const float*)d_in[3];
    const float* Wo = (const float*)d_in[4];
    const int* mask = (const int*)d_in[5];
    float* out = (float*)d_out;

    char* ws = (char*)d_ws;
    size_t off = 0;
    unsigned short* xb  = (unsigned short*)(ws + off); off += (size_t)ROWS * DIM * 2;
    unsigned short* wqb = (unsigned short*)(ws + off); off += (size_t)DIM * DIM * 2;
    unsigned short* wkb = (unsigned short*)(ws + off); off += (size_t)DIM * DIM * 2;
    unsigned short* wvb = (unsigned short*)(ws + off); off += (size_t)DIM * DIM * 2;
    unsigned short* wob = (unsigned short*)(ws + off); off += (size_t)DIM * DIM * 2;
    unsigned short* Qh  = (unsigned short*)(ws + off); off += (size_t)ROWS * DIM * 2;
    unsigned short* Kh  = (unsigned short*)(ws + off); off += (size_t)ROWS * DIM * 2;
    unsigned short* Vtr = (unsigned short*)(ws + off); off += (size_t)ROWS * DIM * 2;
    unsigned short* ctx = (unsigned short*)(ws + off); off += (size_t)ROWS * DIM * 2;
    float* biasf        = (float*)(ws + off);          off += (size_t)BS * SEQ * 4;

    convert_all<<<5128, 256, 0, stream>>>(x, Wq, Wk, Wv, Wo, mask,
                                          xb, wqb, wkb, wvb, wob, biasf);
    gemm_qkv<<<dim3(DIM / 64, ROWS / 64, 3), 256, 0, stream>>>(xb, wqb, wkb, wvb, Qh, Kh, Vtr);
    flash_attn<<<BS * HEADS * (SEQ / 64), 256, 0, stream>>>(Qh, Kh, Vtr, biasf, ctx);
    gemm_proj<<<dim3(DIM / 64, ROWS / 64), 256, 0, stream>>>(ctx, wob, out);

    (void)in_sizes; (void)n_in; (void)out_size; (void)ws_size;
}

// Round 3
// 298.586 us; speedup vs baseline: 1.5721x; 1.5721x over previous
//
#include <hip/hip_runtime.h>
#include <hip/hip_bf16.h>

#define BS 4
#define SEQ 2048
#define DIM 512
#define HEADS 8
#define HD 64
#define ROWS (BS*SEQ)   // 8192
// (1/sqrt(64)) * log2(e) folded into K at projection time
#define SCL2E 0.1803368801111244f
#define NEGB (-1.4426950408889634e6f)   // -1e6 * log2(e)

typedef __attribute__((ext_vector_type(8))) short bf16x8;
typedef __attribute__((ext_vector_type(4))) float floatx4;
typedef unsigned short u16;
typedef unsigned int u32;

__device__ __forceinline__ u16 f2bf(float f) {
    union { float f; unsigned u; } v; v.f = f;
    unsigned r = v.u + 0x7fff + ((v.u >> 16) & 1);
    return (u16)(r >> 16);
}

__device__ __forceinline__ unsigned pack2bf(float a, float b) {
#if __has_builtin(__builtin_amdgcn_cvt_pk_bf16_f32)
    typedef __attribute__((ext_vector_type(2))) __bf16 bf2;
    union { bf2 v; unsigned u; } cv;
    cv.v = __builtin_amdgcn_cvt_pk_bf16_f32(a, b);
    return cv.u;
#else
    return (unsigned)f2bf(a) | ((unsigned)f2bf(b) << 16);
#endif
}

__device__ __forceinline__ float fexp2(float x) {
#if __has_builtin(__builtin_amdgcn_exp2f)
    return __builtin_amdgcn_exp2f(x);     // raw v_exp_f32
#else
    return __expf(x * 0.6931471805599453f);
#endif
}

// async global->LDS, 16B per lane. g is PER-LANE global addr, l is wave-uniform.
__device__ __forceinline__ void gload16(const u16* g, u16* l) {
    __builtin_amdgcn_global_load_lds(
        (const __attribute__((address_space(1))) u32*)g,
        (__attribute__((address_space(3))) u32*)l, 16, 0, 0);
}

// ---------------- fp32 -> bf16 conversion; mask -> exp2-domain bias ---------
__global__ __launch_bounds__(256) void convert_all(
    const float* __restrict__ x, const float* __restrict__ Wq,
    const float* __restrict__ Wk, const float* __restrict__ Wv,
    const float* __restrict__ Wo, const int* __restrict__ mask,
    u16* __restrict__ xb, u16* __restrict__ wqb,
    u16* __restrict__ wkb, u16* __restrict__ wvb,
    u16* __restrict__ wob, float* __restrict__ biasf)
{
    int i = blockIdx.x * 256 + threadIdx.x;
    if (i < 1048576 + 262144) {
        const float* src; u16* dst; int off;
        if (i < 1048576) { src = x; dst = xb; off = i; }
        else {
            int j = i - 1048576; int seg = j >> 16; off = j & 65535;
            src = seg == 0 ? Wq : seg == 1 ? Wk : seg == 2 ? Wv : Wo;
            dst = seg == 0 ? wqb : seg == 1 ? wkb : seg == 2 ? wvb : wob;
        }
        float4 v = ((const float4*)src)[off];
        ushort4 o;
        o.x = f2bf(v.x); o.y = f2bf(v.y); o.z = f2bf(v.z); o.w = f2bf(v.w);
        ((ushort4*)dst)[off] = o;
    } else {
        int jb = i - 1310720;                      // 0..2047
        int4 mv = ((const int4*)mask)[jb];
        float4 bo;
        bo.x = (mv.x == 1) ? 0.f : NEGB;
        bo.y = (mv.y == 1) ? 0.f : NEGB;
        bo.z = (mv.z == 1) ? 0.f : NEGB;
        bo.w = (mv.w == 1) ? 0.f : NEGB;
        ((float4*)biasf)[jb] = bo;
    }
}

// ---------------- QKV projection: C = A @ W^T ------------------------------
// z==0 (Q): head-split (b,h,n,d) bf16.
// z==1 (K): MFMA A-fragment order, pre-scaled by SCL2E:
//   Kf[bh][kt][(nt*2+g)*512 + (quad*16+l16k)*8 + j] = K[key][d]*SCL2E
//   where key=kt*64+nt*16+l16k, d=g*32+quad*8+j.
// z==2 (V): MFMA B-fragment order:
//   Vf[bh][kt][(ct*2+g)*512 + (quadv*16+l16v)*8 + jk] = V[key][d]
//   where key=kt*64+g*32+quadv*8+jk, d=ct*16+l16v.
__global__ __launch_bounds__(256) void gemm_qkv(
    const u16* __restrict__ A,
    const u16* __restrict__ W0, const u16* __restrict__ W1,
    const u16* __restrict__ W2,
    u16* __restrict__ O0, u16* __restrict__ O1, u16* __restrict__ O2)
{
    const u16* Bt = blockIdx.z == 0 ? W0 : blockIdx.z == 1 ? W1 : W2;
    int n0 = blockIdx.x * 64;
    int m0 = blockIdx.y * 64;
    int tid = threadIdx.x;
    int w = tid >> 6, lane = tid & 63, quad = lane >> 4, l16 = lane & 15;

    const u16* Ap = A + (long)(m0 + w*16 + l16) * DIM + quad * 8;
    const u16* Bp = Bt + (long)(n0 + l16) * DIM + quad * 8;

    floatx4 acc[4];
    #pragma unroll
    for (int ct = 0; ct < 4; ct++) acc[ct] = (floatx4){0.f, 0.f, 0.f, 0.f};

    #pragma unroll 2
    for (int k0 = 0; k0 < DIM; k0 += 32) {
        bf16x8 a = *(const bf16x8*)(Ap + k0);
        #pragma unroll
        for (int ct = 0; ct < 4; ct++) {
            bf16x8 b = *(const bf16x8*)(Bp + (long)ct * 16 * DIM + k0);
            acc[ct] = __builtin_amdgcn_mfma_f32_16x16x32_bf16(a, b, acc[ct], 0, 0, 0);
        }
    }

    if (blockIdx.z == 0) {
        #pragma unroll
        for (int ct = 0; ct < 4; ct++)
            #pragma unroll
            for (int r = 0; r < 4; r++) {
                int row = m0 + w*16 + quad*4 + r;   // b*SEQ + n
                int col = n0 + ct*16 + l16;         // h*64 + d
                int b = row >> 11, n = row & 2047, h = col >> 6, d = col & 63;
                O0[(((long)(b * HEADS + h) * SEQ + n) << 6) + d] = f2bf(acc[ct][r]);
            }
    } else if (blockIdx.z == 1) {
        // K fragment-order, scaled
        #pragma unroll
        for (int ct = 0; ct < 4; ct++)
            #pragma unroll
            for (int r = 0; r < 4; r++) {
                int row = m0 + w*16 + quad*4 + r;
                int col = n0 + ct*16 + l16;
                int b = row >> 11, keyn = row & 2047, h = col >> 6, dd = col & 63;
                int kt = keyn >> 6, nt = (keyn >> 4) & 3, l16k = keyn & 15;
                int g = dd >> 5, quadk = (dd >> 3) & 3, j = dd & 7;
                long offv = ((long)((b*HEADS + h)*32 + kt) << 12)
                          + ((nt*2 + g) << 9) + ((quadk*16 + l16k) << 3) + j;
                O1[offv] = f2bf(acc[ct][r] * SCL2E);
            }
    } else {
        // V fragment-order; 4 consecutive keys per lane -> ushort4
        #pragma unroll
        for (int ct = 0; ct < 4; ct++) {
            int rowb = m0 + w*16 + quad*4;
            int col = n0 + ct*16 + l16;
            int b = rowb >> 11, keyn = rowb & 2047, h = col >> 6, dd = col & 63;
            int kt = keyn >> 6, g = (keyn >> 5) & 1, quadv = (keyn >> 3) & 3, jk = keyn & 7;
            int ctv = dd >> 4, l16v = dd & 15;
            long offv = ((long)((b*HEADS + h)*32 + kt) << 12)
                      + ((ctv*2 + g) << 9) + ((quadv*16 + l16v) << 3) + jk;
            ushort4 st;
            st.x = f2bf(acc[ct][0]); st.y = f2bf(acc[ct][1]);
            st.z = f2bf(acc[ct][2]); st.w = f2bf(acc[ct][3]);
            *(ushort4*)&O2[offv] = st;
        }
    }
}

// ---------------- flash attention (S^T orient., LDS dbuf via global_load_lds)
// Block: (b,h,64 q) = 4 waves x 16 q. K/V tiles of 64 keys staged in fragment
// order -> every ds_read_b128 is at (chunk*1KB + lane*16B): conflict-free.
__global__ __launch_bounds__(256, 4) void flash_attn(
    const u16* __restrict__ Q, const u16* __restrict__ Kf,
    const u16* __restrict__ Vf, const float* __restrict__ biasf,
    u16* __restrict__ ctx)
{
    // [0] Kbuf0 4096, [4096] Kbuf1, [8192] Vbuf0, [12288] Vbuf1, [16384] P 4x1024
    __shared__ u16 lds[20480];

    int bx = blockIdx.x;
    int q0 = (bx & 31) * 64;
    int h  = (bx >> 5) & 7;
    int b  = bx >> 8;
    int bh = b * HEADS + h;

    int tid = threadIdx.x;
    int w = tid >> 6, lane = tid & 63, quad = lane >> 4, l16 = lane & 15;

    const u16* Qp = Q + ((long)bh * SEQ + q0 + w*16 + l16) * HD + quad * 8;
    bf16x8 qb0 = *(const bf16x8*)(Qp);
    bf16x8 qb1 = *(const bf16x8*)(Qp + 32);

    const u16* Kbh = Kf + ((long)bh << 17);   // 32 tiles * 4096
    const u16* Vbh = Vf + ((long)bh << 17);
    const float* bbase = biasf + b * SEQ + quad * 4;

    u16* Prow = &lds[16384 + w * 1024 + l16 * 64];
    int swz = l16 & 7;

    // ---- stage tile 0 into buf 0 (wave w: K chunks 2w,2w+1; V same) ----
    {
        const u16* gk = Kbh + (2*w)*512 + lane*8;
        const u16* gv = Vbh + (2*w)*512 + lane*8;
        gload16(gk,       &lds[(2*w)*512]);
        gload16(gk + 512, &lds[(2*w+1)*512]);
        gload16(gv,       &lds[8192 + (2*w)*512]);
        gload16(gv + 512, &lds[8192 + (2*w+1)*512]);
    }
    __syncthreads();

    floatx4 o[4];
    #pragma unroll
    for (int ct = 0; ct < 4; ct++) o[ct] = (floatx4){0.f, 0.f, 0.f, 0.f};
    float m_i = -1e30f, l_i = 0.f;

    for (int t = 0; t < 32; t++) {
        int cur = t & 1;
        // ---- prefetch next tile into other buffer (async, in flight) ----
        if (t < 31) {
            long tb = (long)(t + 1) << 12;
            int nb = cur ^ 1;
            const u16* gk = Kbh + tb + (2*w)*512 + lane*8;
            const u16* gv = Vbh + tb + (2*w)*512 + lane*8;
            gload16(gk,       &lds[nb*4096 + (2*w)*512]);
            gload16(gk + 512, &lds[nb*4096 + (2*w+1)*512]);
            gload16(gv,       &lds[8192 + nb*4096 + (2*w)*512]);
            gload16(gv + 512, &lds[8192 + nb*4096 + (2*w+1)*512]);
        }

        const u16* Kl = &lds[cur * 4096];
        const u16* Vl = &lds[8192 + cur * 4096];

        // ---- S^T = K.Q^T (K pre-scaled) + mask bias (exp2 domain) ----
        floatx4 s[4];
        #pragma unroll
        for (int nt = 0; nt < 4; nt++) {
            float4 bv = *(const float4*)(bbase + t*64 + nt*16);
            bf16x8 ka0 = *(const bf16x8*)(Kl + (nt*2 + 0)*512 + lane*8);
            bf16x8 ka1 = *(const bf16x8*)(Kl + (nt*2 + 1)*512 + lane*8);
            floatx4 tt = (floatx4){0.f, 0.f, 0.f, 0.f};
            tt = __builtin_amdgcn_mfma_f32_16x16x32_bf16(ka0, qb0, tt, 0, 0, 0);
            tt = __builtin_amdgcn_mfma_f32_16x16x32_bf16(ka1, qb1, tt, 0, 0, 0);
            s[nt][0] = tt[0] + bv.x;
            s[nt][1] = tt[1] + bv.y;
            s[nt][2] = tt[2] + bv.z;
            s[nt][3] = tt[3] + bv.w;
        }

        // ---- online softmax (lane owns q=l16 partials over 16 keys) ----
        float vmax = s[0][0];
        #pragma unroll
        for (int nt = 0; nt < 4; nt++)
            #pragma unroll
            for (int r = 0; r < 4; r++) vmax = fmaxf(vmax, s[nt][r]);
        vmax = fmaxf(vmax, __shfl_xor(vmax, 16));
        vmax = fmaxf(vmax, __shfl_xor(vmax, 32));
        float mnew = fmaxf(m_i, vmax);
        float alpha = fexp2(m_i - mnew);
        m_i = mnew;

        float sum = 0.f;
        #pragma unroll
        for (int nt = 0; nt < 4; nt++)
            #pragma unroll
            for (int r = 0; r < 4; r++) {
                s[nt][r] = fexp2(s[nt][r] - mnew);
                sum += s[nt][r];
            }

        // ---- P -> per-wave swizzled LDS rows (8B writes) ----
        #pragma unroll
        for (int nt = 0; nt < 4; nt++) {
            int gx = nt*2 + (quad >> 1);
            uint2 pu;
            pu.x = pack2bf(s[nt][0], s[nt][1]);
            pu.y = pack2bf(s[nt][2], s[nt][3]);
            *(uint2*)(Prow + ((gx ^ swz) << 3) + (quad & 1)*4) = pu;
        }

        sum += __shfl_xor(sum, 16);
        sum += __shfl_xor(sum, 32);
        l_i = l_i * alpha + sum;

        // alpha broadcast to o-rows (q=quad*4+r lives on lane quad*4+r)
        float a0 = __shfl(alpha, quad*4 + 0);
        float a1 = __shfl(alpha, quad*4 + 1);
        float a2 = __shfl(alpha, quad*4 + 2);
        float a3 = __shfl(alpha, quad*4 + 3);
        #pragma unroll
        for (int ct = 0; ct < 4; ct++) {
            o[ct][0] *= a0; o[ct][1] *= a1; o[ct][2] *= a2; o[ct][3] *= a3;
        }

        // ---- O += P @ V ----
        #pragma unroll
        for (int g = 0; g < 2; g++) {
            bf16x8 pa = *(const bf16x8*)(Prow + (((g*4 + quad) ^ swz) << 3));
            #pragma unroll
            for (int ct = 0; ct < 4; ct++) {
                bf16x8 vbf = *(const bf16x8*)(Vl + (ct*2 + g)*512 + lane*8);
                o[ct] = __builtin_amdgcn_mfma_f32_16x16x32_bf16(pa, vbf, o[ct], 0, 0, 0);
            }
        }

        __syncthreads();   // publishes next buffer (drains prefetch), guards overwrite
    }

    // ---- epilogue: ctx[b*SEQ+q][h*64+d] = O / l ----
    float inv = 1.0f / l_i;
    float i0 = __shfl(inv, quad*4 + 0);
    float i1 = __shfl(inv, quad*4 + 1);
    float i2 = __shfl(inv, quad*4 + 2);
    float i3 = __shfl(inv, quad*4 + 3);
    #pragma unroll
    for (int ct = 0; ct < 4; ct++) {
        int col = h * HD + ct*16 + l16;
        long rb = (long)(b * SEQ + q0 + w*16 + quad*4);
        ctx[(rb + 0) * DIM + col] = f2bf(o[ct][0] * i0);
        ctx[(rb + 1) * DIM + col] = f2bf(o[ct][1] * i1);
        ctx[(rb + 2) * DIM + col] = f2bf(o[ct][2] * i2);
        ctx[(rb + 3) * DIM + col] = f2bf(o[ct][3] * i3);
    }
}

// ---------------- output projection: out = ctx @ Wo^T (fp32 out) ------------
__global__ __launch_bounds__(256) void gemm_proj(
    const u16* __restrict__ A, const u16* __restrict__ Bt,
    float* __restrict__ Out)
{
    int n0 = blockIdx.x * 64;
    int m0 = blockIdx.y * 64;
    int tid = threadIdx.x;
    int w = tid >> 6, lane = tid & 63, quad = lane >> 4, l16 = lane & 15;

    const u16* Ap = A + (long)(m0 + w*16 + l16) * DIM + quad * 8;
    const u16* Bp = Bt + (long)(n0 + l16) * DIM + quad * 8;

    floatx4 acc[4];
    #pragma unroll
    for (int ct = 0; ct < 4; ct++) acc[ct] = (floatx4){0.f, 0.f, 0.f, 0.f};

    #pragma unroll 2
    for (int k0 = 0; k0 < DIM; k0 += 32) {
        bf16x8 a = *(const bf16x8*)(Ap + k0);
        #pragma unroll
        for (int ct = 0; ct < 4; ct++) {
            bf16x8 b = *(const bf16x8*)(Bp + (long)ct * 16 * DIM + k0);
            acc[ct] = __builtin_amdgcn_mfma_f32_16x16x32_bf16(a, b, acc[ct], 0, 0, 0);
        }
    }
    #pragma unroll
    for (int ct = 0; ct < 4; ct++) {
        #pragma unroll
        for (int r = 0; r < 4; r++) {
            int row = m0 + w*16 + quad*4 + r;
            int col = n0 + ct*16 + l16;
            Out[(long)row * DIM + col] = acc[ct][r];
        }
    }
}

extern "C" void kernel_launch(void* const* d_in, const int* in_sizes, int n_in,
                              void* d_out, int out_size, void* d_ws, size_t ws_size,
                              hipStream_t stream) {
    const float* x  = (const float*)d_in[0];
    const float* Wq = (const float*)d_in[1];
    const float* Wk = (const float*)d_in[2];
    const float* Wv = (const float*)d_in[3];
    const float* Wo = (const float*)d_in[4];
    const int* mask = (const int*)d_in[5];
    float* out = (float*)d_out;

    char* ws = (char*)d_ws;
    size_t off = 0;
    u16* xb  = (u16*)(ws + off); off += (size_t)ROWS * DIM * 2;
    u16* wqb = (u16*)(ws + off); off += (size_t)DIM * DIM * 2;
    u16* wkb = (u16*)(ws + off); off += (size_t)DIM * DIM * 2;
    u16* wvb = (u16*)(ws + off); off += (size_t)DIM * DIM * 2;
    u16* wob = (u16*)(ws + off); off += (size_t)DIM * DIM * 2;
    u16* Qh  = (u16*)(ws + off); off += (size_t)ROWS * DIM * 2;
    u16* Kfr = (u16*)(ws + off); off += (size_t)ROWS * DIM * 2;
    u16* Vfr = (u16*)(ws + off); off += (size_t)ROWS * DIM * 2;
    u16* ctx = (u16*)(ws + off); off += (size_t)ROWS * DIM * 2;
    float* biasf = (float*)(ws + off); off += (size_t)BS * SEQ * 4;

    convert_all<<<5128, 256, 0, stream>>>(x, Wq, Wk, Wv, Wo, mask,
                                          xb, wqb, wkb, wvb, wob, biasf);
    gemm_qkv<<<dim3(DIM / 64, ROWS / 64, 3), 256, 0, stream>>>(xb, wqb, wkb, wvb, Qh, Kfr, Vfr);
    flash_attn<<<BS * HEADS * (SEQ / 64), 256, 0, stream>>>(Qh, Kfr, Vfr, biasf, ctx);
    gemm_proj<<<dim3(DIM / 64, ROWS / 64), 256, 0, stream>>>(ctx, wob, out);

    (void)in_sizes; (void)n_in; (void)out_size; (void)ws_size;
}

// Round 4
// 182.499 us; speedup vs baseline: 2.5722x; 1.6361x over previous
//
#include <hip/hip_runtime.h>
#include <hip/hip_bf16.h>

#define BS 4
#define SEQ 2048
#define DIM 512
#define HEADS 8
#define HD 64
#define ROWS (BS*SEQ)   // 8192
// (1/sqrt(64)) * log2(e) folded into K at projection time
#define SCL2E 0.1803368801111244f
#define NEGB (-1.4426950408889634e6f)   // -1e6 * log2(e)

typedef __attribute__((ext_vector_type(8))) short bf16x8;
typedef __attribute__((ext_vector_type(4))) float floatx4;
typedef unsigned short u16;
typedef unsigned int u32;

__device__ __forceinline__ u16 f2bf(float f) {
    union { float f; unsigned u; } v; v.f = f;
    unsigned r = v.u + 0x7fff + ((v.u >> 16) & 1);
    return (u16)(r >> 16);
}

__device__ __forceinline__ unsigned pack2bf(float a, float b) {
#if __has_builtin(__builtin_amdgcn_cvt_pk_bf16_f32)
    typedef __attribute__((ext_vector_type(2))) __bf16 bf2;
    union { bf2 v; unsigned u; } cv;
    cv.v = __builtin_amdgcn_cvt_pk_bf16_f32(a, b);
    return cv.u;
#else
    return (unsigned)f2bf(a) | ((unsigned)f2bf(b) << 16);
#endif
}

__device__ __forceinline__ float fexp2(float x) {
#if __has_builtin(__builtin_amdgcn_exp2f)
    return __builtin_amdgcn_exp2f(x);     // raw v_exp_f32
#else
    return __expf(x * 0.6931471805599453f);
#endif
}

// async global->LDS, 16B per lane. g is PER-LANE global addr, l is wave-uniform.
__device__ __forceinline__ void gload16(const u16* g, u16* l) {
    __builtin_amdgcn_global_load_lds(
        (const __attribute__((address_space(1))) u32*)g,
        (__attribute__((address_space(3))) u32*)l, 16, 0, 0);
}

// ---------------- fp32 -> bf16 conversion; mask -> exp2-domain bias ---------
__global__ __launch_bounds__(256) void convert_all(
    const float* __restrict__ x, const float* __restrict__ Wq,
    const float* __restrict__ Wk, const float* __restrict__ Wv,
    const float* __restrict__ Wo, const int* __restrict__ mask,
    u16* __restrict__ xb, u16* __restrict__ wqb,
    u16* __restrict__ wkb, u16* __restrict__ wvb,
    u16* __restrict__ wob, float* __restrict__ biasf)
{
    int i = blockIdx.x * 256 + threadIdx.x;
    if (i < 1048576 + 262144) {
        const float* src; u16* dst; int off;
        if (i < 1048576) { src = x; dst = xb; off = i; }
        else {
            int j = i - 1048576; int seg = j >> 16; off = j & 65535;
            src = seg == 0 ? Wq : seg == 1 ? Wk : seg == 2 ? Wv : Wo;
            dst = seg == 0 ? wqb : seg == 1 ? wkb : seg == 2 ? wvb : wob;
        }
        float4 v = ((const float4*)src)[off];
        ushort4 o;
        o.x = f2bf(v.x); o.y = f2bf(v.y); o.z = f2bf(v.z); o.w = f2bf(v.w);
        ((ushort4*)dst)[off] = o;
    } else {
        int jb = i - 1310720;                      // 0..2047
        int4 mv = ((const int4*)mask)[jb];
        float4 bo;
        bo.x = (mv.x == 1) ? 0.f : NEGB;
        bo.y = (mv.y == 1) ? 0.f : NEGB;
        bo.z = (mv.z == 1) ? 0.f : NEGB;
        bo.w = (mv.w == 1) ? 0.f : NEGB;
        ((float4*)biasf)[jb] = bo;
    }
}

// ---------------- fused QKV GEMM: C = x @ [Wq;Wk;Wv]^T ----------------------
// 128x128 tile, BK=64, m97 structure (global_load_lds + single-buf 2-barrier).
// LDS tiles XOR-swizzled: lane (r=ll>>3,c=ll&7) stages global chunk c^r, so
// fragment ds_read_b128 is <=2-way per phase (free).
// Epilogue by n-segment: 0=Q head-split, 1=K frag-order*SCL2E, 2=V frag-order.
__global__ __launch_bounds__(256, 3) void gemm_qkv_fused(
    const u16* __restrict__ A, const u16* __restrict__ Wcat,
    u16* __restrict__ Oq, u16* __restrict__ Okf, u16* __restrict__ Ovf)
{
    __shared__ u16 ldsA[8192];   // 128 rows x 64, chunk i (1KB) = rows 8i..8i+7
    __shared__ u16 ldsB[8192];

    int n0 = blockIdx.x * 128;   // 0..1535
    int m0 = blockIdx.y * 128;
    int tid = threadIdx.x;
    int w = tid >> 6, lane = tid & 63, quad = lane >> 4, l16 = lane & 15;
    int mo = (w & 1) * 64, no = (w >> 1) * 64;
    int l7 = l16 & 7;

    int sr = lane >> 3, sc = lane & 7, gc = sc ^ sr;   // staging row/chunk-swz
    const u16* gA0 = A    + (long)(m0 + sr) * DIM + gc * 8;
    const u16* gB0 = Wcat + (long)(n0 + sr) * DIM + gc * 8;

    floatx4 acc[4][4];
    #pragma unroll
    for (int mt = 0; mt < 4; mt++)
        #pragma unroll
        for (int nt = 0; nt < 4; nt++) acc[mt][nt] = (floatx4){0.f,0.f,0.f,0.f};

    for (int k0 = 0; k0 < DIM; k0 += 64) {
        // ---- stage A,B tiles (wave w: chunks 4w..4w+3 of each) ----
        #pragma unroll
        for (int i = 0; i < 4; i++) {
            int ch = w * 4 + i;
            gload16(gA0 + (long)ch * 8 * DIM + k0, &ldsA[ch * 512]);
            gload16(gB0 + (long)ch * 8 * DIM + k0, &ldsB[ch * 512]);
        }
        __syncthreads();

        #pragma unroll
        for (int kc = 0; kc < 2; kc++) {
            int swz = ((kc * 4 + quad) ^ l7) * 8;
            bf16x8 af[4], bf[4];
            #pragma unroll
            for (int t4 = 0; t4 < 4; t4++) {
                af[t4] = *(const bf16x8*)&ldsA[(mo + t4*16 + l16) * 64 + swz];
                bf[t4] = *(const bf16x8*)&ldsB[(no + t4*16 + l16) * 64 + swz];
            }
            #pragma unroll
            for (int mt = 0; mt < 4; mt++)
                #pragma unroll
                for (int nt = 0; nt < 4; nt++)
                    acc[mt][nt] = __builtin_amdgcn_mfma_f32_16x16x32_bf16(
                        af[mt], bf[nt], acc[mt][nt], 0, 0, 0);
        }
        __syncthreads();
    }

    int seg = n0 >> 9;    // block-uniform: 0=Q 1=K 2=V
    if (seg == 0) {
        #pragma unroll
        for (int mt = 0; mt < 4; mt++)
            #pragma unroll
            for (int nt = 0; nt < 4; nt++)
                #pragma unroll
                for (int r = 0; r < 4; r++) {
                    int row = m0 + mo + mt*16 + quad*4 + r;      // b*SEQ+n
                    int col9 = (n0 + no + nt*16 + l16) & 511;    // h*64+d
                    int b = row >> 11, n = row & 2047, h = col9 >> 6, d = col9 & 63;
                    Oq[(((long)(b * HEADS + h) * SEQ + n) << 6) + d] = f2bf(acc[mt][nt][r]);
                }
    } else if (seg == 1) {
        #pragma unroll
        for (int mt = 0; mt < 4; mt++)
            #pragma unroll
            for (int nt = 0; nt < 4; nt++)
                #pragma unroll
                for (int r = 0; r < 4; r++) {
                    int row = m0 + mo + mt*16 + quad*4 + r;
                    int col9 = (n0 + no + nt*16 + l16) & 511;
                    int b = row >> 11, keyn = row & 2047, h = col9 >> 6, dd = col9 & 63;
                    int kt = keyn >> 6, ntk = (keyn >> 4) & 3, l16k = keyn & 15;
                    int g = dd >> 5, quadk = (dd >> 3) & 3, j = dd & 7;
                    long offv = ((long)((b*HEADS + h)*32 + kt) << 12)
                              + ((ntk*2 + g) << 9) + ((quadk*16 + l16k) << 3) + j;
                    Okf[offv] = f2bf(acc[mt][nt][r] * SCL2E);
                }
    } else {
        #pragma unroll
        for (int mt = 0; mt < 4; mt++)
            #pragma unroll
            for (int nt = 0; nt < 4; nt++) {
                int rowb = m0 + mo + mt*16 + quad*4;
                int col9 = (n0 + no + nt*16 + l16) & 511;
                int b = rowb >> 11, keyn = rowb & 2047, h = col9 >> 6, dd = col9 & 63;
                int kt = keyn >> 6, g = (keyn >> 5) & 1, quadv = (keyn >> 3) & 3, jk = keyn & 7;
                int ctv = dd >> 4, l16v = dd & 15;
                long offv = ((long)((b*HEADS + h)*32 + kt) << 12)
                          + ((ctv*2 + g) << 9) + ((quadv*16 + l16v) << 3) + jk;
                ushort4 st;
                st.x = f2bf(acc[mt][nt][0]); st.y = f2bf(acc[mt][nt][1]);
                st.z = f2bf(acc[mt][nt][2]); st.w = f2bf(acc[mt][nt][3]);
                *(ushort4*)&Ovf[offv] = st;
            }
    }
}

// ---------------- flash attention (S^T orient., LDS dbuf via global_load_lds)
__global__ __launch_bounds__(256, 4) void flash_attn(
    const u16* __restrict__ Q, const u16* __restrict__ Kf,
    const u16* __restrict__ Vf, const float* __restrict__ biasf,
    u16* __restrict__ ctx)
{
    // [0] Kbuf0 4096, [4096] Kbuf1, [8192] Vbuf0, [12288] Vbuf1, [16384] P 4x1024
    __shared__ u16 lds[20480];

    int bx = blockIdx.x;
    int q0 = (bx & 31) * 64;
    int h  = (bx >> 5) & 7;
    int b  = bx >> 8;
    int bh = b * HEADS + h;

    int tid = threadIdx.x;
    int w = tid >> 6, lane = tid & 63, quad = lane >> 4, l16 = lane & 15;

    const u16* Qp = Q + ((long)bh * SEQ + q0 + w*16 + l16) * HD + quad * 8;
    bf16x8 qb0 = *(const bf16x8*)(Qp);
    bf16x8 qb1 = *(const bf16x8*)(Qp + 32);

    const u16* Kbh = Kf + ((long)bh << 17);
    const u16* Vbh = Vf + ((long)bh << 17);
    const float* bbase = biasf + b * SEQ + quad * 4;

    u16* Prow = &lds[16384 + w * 1024 + l16 * 64];
    int swz = l16 & 7;

    {
        const u16* gk = Kbh + (2*w)*512 + lane*8;
        const u16* gv = Vbh + (2*w)*512 + lane*8;
        gload16(gk,       &lds[(2*w)*512]);
        gload16(gk + 512, &lds[(2*w+1)*512]);
        gload16(gv,       &lds[8192 + (2*w)*512]);
        gload16(gv + 512, &lds[8192 + (2*w+1)*512]);
    }
    __syncthreads();

    floatx4 o[4];
    #pragma unroll
    for (int ct = 0; ct < 4; ct++) o[ct] = (floatx4){0.f, 0.f, 0.f, 0.f};
    float m_i = -1e30f, l_i = 0.f;

    for (int t = 0; t < 32; t++) {
        int cur = t & 1;
        if (t < 31) {
            long tb = (long)(t + 1) << 12;
            int nb = cur ^ 1;
            const u16* gk = Kbh + tb + (2*w)*512 + lane*8;
            const u16* gv = Vbh + tb + (2*w)*512 + lane*8;
            gload16(gk,       &lds[nb*4096 + (2*w)*512]);
            gload16(gk + 512, &lds[nb*4096 + (2*w+1)*512]);
            gload16(gv,       &lds[8192 + nb*4096 + (2*w)*512]);
            gload16(gv + 512, &lds[8192 + nb*4096 + (2*w+1)*512]);
        }

        const u16* Kl = &lds[cur * 4096];
        const u16* Vl = &lds[8192 + cur * 4096];

        floatx4 s[4];
        #pragma unroll
        for (int nt = 0; nt < 4; nt++) {
            float4 bv = *(const float4*)(bbase + t*64 + nt*16);
            bf16x8 ka0 = *(const bf16x8*)(Kl + (nt*2 + 0)*512 + lane*8);
            bf16x8 ka1 = *(const bf16x8*)(Kl + (nt*2 + 1)*512 + lane*8);
            floatx4 tt = (floatx4){0.f, 0.f, 0.f, 0.f};
            tt = __builtin_amdgcn_mfma_f32_16x16x32_bf16(ka0, qb0, tt, 0, 0, 0);
            tt = __builtin_amdgcn_mfma_f32_16x16x32_bf16(ka1, qb1, tt, 0, 0, 0);
            s[nt][0] = tt[0] + bv.x;
            s[nt][1] = tt[1] + bv.y;
            s[nt][2] = tt[2] + bv.z;
            s[nt][3] = tt[3] + bv.w;
        }

        float vmax = s[0][0];
        #pragma unroll
        for (int nt = 0; nt < 4; nt++)
            #pragma unroll
            for (int r = 0; r < 4; r++) vmax = fmaxf(vmax, s[nt][r]);
        vmax = fmaxf(vmax, __shfl_xor(vmax, 16));
        vmax = fmaxf(vmax, __shfl_xor(vmax, 32));
        float mnew = fmaxf(m_i, vmax);
        float alpha = fexp2(m_i - mnew);
        m_i = mnew;

        float sum = 0.f;
        #pragma unroll
        for (int nt = 0; nt < 4; nt++)
            #pragma unroll
            for (int r = 0; r < 4; r++) {
                s[nt][r] = fexp2(s[nt][r] - mnew);
                sum += s[nt][r];
            }

        #pragma unroll
        for (int nt = 0; nt < 4; nt++) {
            int gx = nt*2 + (quad >> 1);
            uint2 pu;
            pu.x = pack2bf(s[nt][0], s[nt][1]);
            pu.y = pack2bf(s[nt][2], s[nt][3]);
            *(uint2*)(Prow + ((gx ^ swz) << 3) + (quad & 1)*4) = pu;
        }

        sum += __shfl_xor(sum, 16);
        sum += __shfl_xor(sum, 32);
        l_i = l_i * alpha + sum;

        float a0 = __shfl(alpha, quad*4 + 0);
        float a1 = __shfl(alpha, quad*4 + 1);
        float a2 = __shfl(alpha, quad*4 + 2);
        float a3 = __shfl(alpha, quad*4 + 3);
        #pragma unroll
        for (int ct = 0; ct < 4; ct++) {
            o[ct][0] *= a0; o[ct][1] *= a1; o[ct][2] *= a2; o[ct][3] *= a3;
        }

        #pragma unroll
        for (int g = 0; g < 2; g++) {
            bf16x8 pa = *(const bf16x8*)(Prow + (((g*4 + quad) ^ swz) << 3));
            #pragma unroll
            for (int ct = 0; ct < 4; ct++) {
                bf16x8 vbf = *(const bf16x8*)(Vl + (ct*2 + g)*512 + lane*8);
                o[ct] = __builtin_amdgcn_mfma_f32_16x16x32_bf16(pa, vbf, o[ct], 0, 0, 0);
            }
        }

        __syncthreads();
    }

    float inv = 1.0f / l_i;
    float i0 = __shfl(inv, quad*4 + 0);
    float i1 = __shfl(inv, quad*4 + 1);
    float i2 = __shfl(inv, quad*4 + 2);
    float i3 = __shfl(inv, quad*4 + 3);
    #pragma unroll
    for (int ct = 0; ct < 4; ct++) {
        int col = h * HD + ct*16 + l16;
        long rb = (long)(b * SEQ + q0 + w*16 + quad*4);
        ctx[(rb + 0) * DIM + col] = f2bf(o[ct][0] * i0);
        ctx[(rb + 1) * DIM + col] = f2bf(o[ct][1] * i1);
        ctx[(rb + 2) * DIM + col] = f2bf(o[ct][2] * i2);
        ctx[(rb + 3) * DIM + col] = f2bf(o[ct][3] * i3);
    }
}

// ---------------- output projection (same m97 structure, fp32 out) ----------
__global__ __launch_bounds__(256, 3) void gemm_proj(
    const u16* __restrict__ A, const u16* __restrict__ Bt,
    float* __restrict__ Out)
{
    __shared__ u16 ldsA[8192];
    __shared__ u16 ldsB[8192];

    int n0 = blockIdx.x * 128;
    int m0 = blockIdx.y * 128;
    int tid = threadIdx.x;
    int w = tid >> 6, lane = tid & 63, quad = lane >> 4, l16 = lane & 15;
    int mo = (w & 1) * 64, no = (w >> 1) * 64;
    int l7 = l16 & 7;

    int sr = lane >> 3, sc = lane & 7, gc = sc ^ sr;
    const u16* gA0 = A  + (long)(m0 + sr) * DIM + gc * 8;
    const u16* gB0 = Bt + (long)(n0 + sr) * DIM + gc * 8;

    floatx4 acc[4][4];
    #pragma unroll
    for (int mt = 0; mt < 4; mt++)
        #pragma unroll
        for (int nt = 0; nt < 4; nt++) acc[mt][nt] = (floatx4){0.f,0.f,0.f,0.f};

    for (int k0 = 0; k0 < DIM; k0 += 64) {
        #pragma unroll
        for (int i = 0; i < 4; i++) {
            int ch = w * 4 + i;
            gload16(gA0 + (long)ch * 8 * DIM + k0, &ldsA[ch * 512]);
            gload16(gB0 + (long)ch * 8 * DIM + k0, &ldsB[ch * 512]);
        }
        __syncthreads();

        #pragma unroll
        for (int kc = 0; kc < 2; kc++) {
            int swz = ((kc * 4 + quad) ^ l7) * 8;
            bf16x8 af[4], bf[4];
            #pragma unroll
            for (int t4 = 0; t4 < 4; t4++) {
                af[t4] = *(const bf16x8*)&ldsA[(mo + t4*16 + l16) * 64 + swz];
                bf[t4] = *(const bf16x8*)&ldsB[(no + t4*16 + l16) * 64 + swz];
            }
            #pragma unroll
            for (int mt = 0; mt < 4; mt++)
                #pragma unroll
                for (int nt = 0; nt < 4; nt++)
                    acc[mt][nt] = __builtin_amdgcn_mfma_f32_16x16x32_bf16(
                        af[mt], bf[nt], acc[mt][nt], 0, 0, 0);
        }
        __syncthreads();
    }

    #pragma unroll
    for (int mt = 0; mt < 4; mt++)
        #pragma unroll
        for (int nt = 0; nt < 4; nt++)
            #pragma unroll
            for (int r = 0; r < 4; r++) {
                int row = m0 + mo + mt*16 + quad*4 + r;
                int col = n0 + no + nt*16 + l16;
                Out[(long)row * DIM + col] = acc[mt][nt][r];
            }
}

extern "C" void kernel_launch(void* const* d_in, const int* in_sizes, int n_in,
                              void* d_out, int out_size, void* d_ws, size_t ws_size,
                              hipStream_t stream) {
    const float* x  = (const float*)d_in[0];
    const float* Wq = (const float*)d_in[1];
    const float* Wk = (const float*)d_in[2];
    const float* Wv = (const float*)d_in[3];
    const float* Wo = (const float*)d_in[4];
    const int* mask = (const int*)d_in[5];
    float* out = (float*)d_out;

    char* ws = (char*)d_ws;
    size_t off = 0;
    u16* xb  = (u16*)(ws + off); off += (size_t)ROWS * DIM * 2;
    u16* wqb = (u16*)(ws + off); off += (size_t)DIM * DIM * 2;   // wq/wk/wv contiguous = Wcat
    u16* wkb = (u16*)(ws + off); off += (size_t)DIM * DIM * 2;
    u16* wvb = (u16*)(ws + off); off += (size_t)DIM * DIM * 2;
    u16* wob = (u16*)(ws + off); off += (size_t)DIM * DIM * 2;
    u16* Qh  = (u16*)(ws + off); off += (size_t)ROWS * DIM * 2;
    u16* Kfr = (u16*)(ws + off); off += (size_t)ROWS * DIM * 2;
    u16* Vfr = (u16*)(ws + off); off += (size_t)ROWS * DIM * 2;
    u16* ctx = (u16*)(ws + off); off += (size_t)ROWS * DIM * 2;
    float* biasf = (float*)(ws + off); off += (size_t)BS * SEQ * 4;

    convert_all<<<5128, 256, 0, stream>>>(x, Wq, Wk, Wv, Wo, mask,
                                          xb, wqb, wkb, wvb, wob, biasf);
    gemm_qkv_fused<<<dim3(12, 64), 256, 0, stream>>>(xb, wqb, Qh, Kfr, Vfr);
    flash_attn<<<BS * HEADS * (SEQ / 64), 256, 0, stream>>>(Qh, Kfr, Vfr, biasf, ctx);
    gemm_proj<<<dim3(4, 64), 256, 0, stream>>>(ctx, wob, out);

    (void)in_sizes; (void)n_in; (void)out_size; (void)ws_size;
}

// Round 5
// 174.513 us; speedup vs baseline: 2.6899x; 1.0458x over previous
//
#include <hip/hip_runtime.h>
#include <hip/hip_bf16.h>

#define BS 4
#define SEQ 2048
#define DIM 512
#define HEADS 8
#define HD 64
#define ROWS (BS*SEQ)   // 8192
// (1/sqrt(64)) * log2(e) folded into K at projection time
#define SCL2E 0.1803368801111244f
#define NEGB (-1.4426950408889634e6f)   // -1e6 * log2(e)

typedef __attribute__((ext_vector_type(8))) short bf16x8;
typedef __attribute__((ext_vector_type(4))) float floatx4;
typedef unsigned short u16;
typedef unsigned int u32;

__device__ __forceinline__ u16 f2bf(float f) {
    union { float f; unsigned u; } v; v.f = f;
    unsigned r = v.u + 0x7fff + ((v.u >> 16) & 1);
    return (u16)(r >> 16);
}

__device__ __forceinline__ unsigned pack2bf(float a, float b) {
#if __has_builtin(__builtin_amdgcn_cvt_pk_bf16_f32)
    typedef __attribute__((ext_vector_type(2))) __bf16 bf2;
    union { bf2 v; unsigned u; } cv;
    cv.v = __builtin_amdgcn_cvt_pk_bf16_f32(a, b);
    return cv.u;
#else
    return (unsigned)f2bf(a) | ((unsigned)f2bf(b) << 16);
#endif
}

__device__ __forceinline__ float fexp2(float x) {
#if __has_builtin(__builtin_amdgcn_exp2f)
    return __builtin_amdgcn_exp2f(x);     // raw v_exp_f32
#else
    return __expf(x * 0.6931471805599453f);
#endif
}

// async global->LDS, 16B per lane. g is PER-LANE global addr, l is wave-uniform.
__device__ __forceinline__ void gload16(const u16* g, u16* l) {
    __builtin_amdgcn_global_load_lds(
        (const __attribute__((address_space(1))) u32*)g,
        (__attribute__((address_space(3))) u32*)l, 16, 0, 0);
}

// ---------------- fp32 -> bf16 conversion; mask -> exp2-domain bias ---------
__global__ __launch_bounds__(256) void convert_all(
    const float* __restrict__ x, const float* __restrict__ Wq,
    const float* __restrict__ Wk, const float* __restrict__ Wv,
    const float* __restrict__ Wo, const int* __restrict__ mask,
    u16* __restrict__ xb, u16* __restrict__ wqb,
    u16* __restrict__ wkb, u16* __restrict__ wvb,
    u16* __restrict__ wob, float* __restrict__ biasf)
{
    int i = blockIdx.x * 256 + threadIdx.x;
    if (i < 1048576 + 262144) {
        const float* src; u16* dst; int off;
        if (i < 1048576) { src = x; dst = xb; off = i; }
        else {
            int j = i - 1048576; int seg = j >> 16; off = j & 65535;
            src = seg == 0 ? Wq : seg == 1 ? Wk : seg == 2 ? Wv : Wo;
            dst = seg == 0 ? wqb : seg == 1 ? wkb : seg == 2 ? wvb : wob;
        }
        float4 v = ((const float4*)src)[off];
        ushort4 o;
        o.x = f2bf(v.x); o.y = f2bf(v.y); o.z = f2bf(v.z); o.w = f2bf(v.w);
        ((ushort4*)dst)[off] = o;
    } else {
        int jb = i - 1310720;                      // 0..2047
        int4 mv = ((const int4*)mask)[jb];
        float4 bo;
        bo.x = (mv.x == 1) ? 0.f : NEGB;
        bo.y = (mv.y == 1) ? 0.f : NEGB;
        bo.z = (mv.z == 1) ? 0.f : NEGB;
        bo.w = (mv.w == 1) ? 0.f : NEGB;
        ((float4*)biasf)[jb] = bo;
    }
}

// ---------------- fused QKV GEMM: C = x @ [Wq;Wk;Wv]^T ----------------------
__global__ __launch_bounds__(256, 3) void gemm_qkv_fused(
    const u16* __restrict__ A, const u16* __restrict__ Wcat,
    u16* __restrict__ Oq, u16* __restrict__ Okf, u16* __restrict__ Ovf)
{
    __shared__ u16 ldsA[8192];   // 128 rows x 64, chunk i (1KB) = rows 8i..8i+7
    __shared__ u16 ldsB[8192];

    int n0 = blockIdx.x * 128;   // 0..1535
    int m0 = blockIdx.y * 128;
    int tid = threadIdx.x;
    int w = tid >> 6, lane = tid & 63, quad = lane >> 4, l16 = lane & 15;
    int mo = (w & 1) * 64, no = (w >> 1) * 64;
    int l7 = l16 & 7;

    int sr = lane >> 3, sc = lane & 7, gc = sc ^ sr;   // staging row/chunk-swz
    const u16* gA0 = A    + (long)(m0 + sr) * DIM + gc * 8;
    const u16* gB0 = Wcat + (long)(n0 + sr) * DIM + gc * 8;

    floatx4 acc[4][4];
    #pragma unroll
    for (int mt = 0; mt < 4; mt++)
        #pragma unroll
        for (int nt = 0; nt < 4; nt++) acc[mt][nt] = (floatx4){0.f,0.f,0.f,0.f};

    for (int k0 = 0; k0 < DIM; k0 += 64) {
        #pragma unroll
        for (int i = 0; i < 4; i++) {
            int ch = w * 4 + i;
            gload16(gA0 + (long)ch * 8 * DIM + k0, &ldsA[ch * 512]);
            gload16(gB0 + (long)ch * 8 * DIM + k0, &ldsB[ch * 512]);
        }
        __syncthreads();

        #pragma unroll
        for (int kc = 0; kc < 2; kc++) {
            int swz = ((kc * 4 + quad) ^ l7) * 8;
            bf16x8 af[4], bf[4];
            #pragma unroll
            for (int t4 = 0; t4 < 4; t4++) {
                af[t4] = *(const bf16x8*)&ldsA[(mo + t4*16 + l16) * 64 + swz];
                bf[t4] = *(const bf16x8*)&ldsB[(no + t4*16 + l16) * 64 + swz];
            }
            #pragma unroll
            for (int mt = 0; mt < 4; mt++)
                #pragma unroll
                for (int nt = 0; nt < 4; nt++)
                    acc[mt][nt] = __builtin_amdgcn_mfma_f32_16x16x32_bf16(
                        af[mt], bf[nt], acc[mt][nt], 0, 0, 0);
        }
        __syncthreads();
    }

    int seg = n0 >> 9;    // block-uniform: 0=Q 1=K 2=V
    if (seg == 0) {
        #pragma unroll
        for (int mt = 0; mt < 4; mt++)
            #pragma unroll
            for (int nt = 0; nt < 4; nt++)
                #pragma unroll
                for (int r = 0; r < 4; r++) {
                    int row = m0 + mo + mt*16 + quad*4 + r;      // b*SEQ+n
                    int col9 = (n0 + no + nt*16 + l16) & 511;    // h*64+d
                    int b = row >> 11, n = row & 2047, h = col9 >> 6, d = col9 & 63;
                    Oq[(((long)(b * HEADS + h) * SEQ + n) << 6) + d] = f2bf(acc[mt][nt][r]);
                }
    } else if (seg == 1) {
        #pragma unroll
        for (int mt = 0; mt < 4; mt++)
            #pragma unroll
            for (int nt = 0; nt < 4; nt++)
                #pragma unroll
                for (int r = 0; r < 4; r++) {
                    int row = m0 + mo + mt*16 + quad*4 + r;
                    int col9 = (n0 + no + nt*16 + l16) & 511;
                    int b = row >> 11, keyn = row & 2047, h = col9 >> 6, dd = col9 & 63;
                    int kt = keyn >> 6, ntk = (keyn >> 4) & 3, l16k = keyn & 15;
                    int g = dd >> 5, quadk = (dd >> 3) & 3, j = dd & 7;
                    long offv = ((long)((b*HEADS + h)*32 + kt) << 12)
                              + ((ntk*2 + g) << 9) + ((quadk*16 + l16k) << 3) + j;
                    Okf[offv] = f2bf(acc[mt][nt][r] * SCL2E);
                }
    } else {
        #pragma unroll
        for (int mt = 0; mt < 4; mt++)
            #pragma unroll
            for (int nt = 0; nt < 4; nt++) {
                int rowb = m0 + mo + mt*16 + quad*4;
                int col9 = (n0 + no + nt*16 + l16) & 511;
                int b = rowb >> 11, keyn = rowb & 2047, h = col9 >> 6, dd = col9 & 63;
                int kt = keyn >> 6, g = (keyn >> 5) & 1, quadv = (keyn >> 3) & 3, jk = keyn & 7;
                int ctv = dd >> 4, l16v = dd & 15;
                long offv = ((long)((b*HEADS + h)*32 + kt) << 12)
                          + ((ctv*2 + g) << 9) + ((quadv*16 + l16v) << 3) + jk;
                ushort4 st;
                st.x = f2bf(acc[mt][nt][0]); st.y = f2bf(acc[mt][nt][1]);
                st.z = f2bf(acc[mt][nt][2]); st.w = f2bf(acc[mt][nt][3]);
                *(ushort4*)&Ovf[offv] = st;
            }
    }
}

// ---------------- flash attention: fixed-max streaming softmax --------------
// Logits bounded (|s*log2e| ~< 9 by construction; exp2 overflow needs >126),
// so skip running-max/alpha entirely: p = exp2(s + bias), l = plain sum.
// Bias enters as the MFMA C-initializer (costs 0 VALU). No cross-lane ops in
// the tile loop; l reduced over quads once at the end.
__global__ __launch_bounds__(256, 4) void flash_attn(
    const u16* __restrict__ Q, const u16* __restrict__ Kf,
    const u16* __restrict__ Vf, const float* __restrict__ biasf,
    u16* __restrict__ ctx)
{
    // [0] Kbuf0 4096, [4096] Kbuf1, [8192] Vbuf0, [12288] Vbuf1, [16384] P 4x1024
    __shared__ u16 lds[20480];

    int bx = blockIdx.x;
    int q0 = (bx & 31) * 64;
    int h  = (bx >> 5) & 7;
    int b  = bx >> 8;
    int bh = b * HEADS + h;

    int tid = threadIdx.x;
    int w = tid >> 6, lane = tid & 63, quad = lane >> 4, l16 = lane & 15;

    const u16* Qp = Q + ((long)bh * SEQ + q0 + w*16 + l16) * HD + quad * 8;
    bf16x8 qb0 = *(const bf16x8*)(Qp);
    bf16x8 qb1 = *(const bf16x8*)(Qp + 32);

    const u16* Kbh = Kf + ((long)bh << 17);
    const u16* Vbh = Vf + ((long)bh << 17);
    const float* bbase = biasf + b * SEQ + quad * 4;

    u16* Prow = &lds[16384 + w * 1024 + l16 * 64];
    int swz = l16 & 7;

    {
        const u16* gk = Kbh + (2*w)*512 + lane*8;
        const u16* gv = Vbh + (2*w)*512 + lane*8;
        gload16(gk,       &lds[(2*w)*512]);
        gload16(gk + 512, &lds[(2*w+1)*512]);
        gload16(gv,       &lds[8192 + (2*w)*512]);
        gload16(gv + 512, &lds[8192 + (2*w+1)*512]);
    }
    __syncthreads();

    floatx4 o[4];
    #pragma unroll
    for (int ct = 0; ct < 4; ct++) o[ct] = (floatx4){0.f, 0.f, 0.f, 0.f};
    float lsum = 0.f;    // per-lane partial denominator (lane owns q = l16)

    for (int t = 0; t < 32; t++) {
        int cur = t & 1;
        if (t < 31) {
            long tb = (long)(t + 1) << 12;
            int nb = cur ^ 1;
            const u16* gk = Kbh + tb + (2*w)*512 + lane*8;
            const u16* gv = Vbh + tb + (2*w)*512 + lane*8;
            gload16(gk,       &lds[nb*4096 + (2*w)*512]);
            gload16(gk + 512, &lds[nb*4096 + (2*w+1)*512]);
            gload16(gv,       &lds[8192 + nb*4096 + (2*w)*512]);
            gload16(gv + 512, &lds[8192 + nb*4096 + (2*w+1)*512]);
        }

        const u16* Kl = &lds[cur * 4096];
        const u16* Vl = &lds[8192 + cur * 4096];

        // ---- P^T tile: p = exp2(K.Q^T + bias); bias rides in as C-init ----
        #pragma unroll
        for (int nt = 0; nt < 4; nt++) {
            float4 bv = *(const float4*)(bbase + t*64 + nt*16);
            bf16x8 ka0 = *(const bf16x8*)(Kl + (nt*2 + 0)*512 + lane*8);
            bf16x8 ka1 = *(const bf16x8*)(Kl + (nt*2 + 1)*512 + lane*8);
            floatx4 tt;
            tt[0] = bv.x; tt[1] = bv.y; tt[2] = bv.z; tt[3] = bv.w;
            tt = __builtin_amdgcn_mfma_f32_16x16x32_bf16(ka0, qb0, tt, 0, 0, 0);
            tt = __builtin_amdgcn_mfma_f32_16x16x32_bf16(ka1, qb1, tt, 0, 0, 0);
            float p0 = fexp2(tt[0]);
            float p1 = fexp2(tt[1]);
            float p2 = fexp2(tt[2]);
            float p3 = fexp2(tt[3]);
            lsum += (p0 + p1) + (p2 + p3);
            int gx = nt*2 + (quad >> 1);
            uint2 pu;
            pu.x = pack2bf(p0, p1);
            pu.y = pack2bf(p2, p3);
            *(uint2*)(Prow + ((gx ^ swz) << 3) + (quad & 1)*4) = pu;
        }

        // ---- O += P @ V (P via per-wave LDS round-trip, same-wave lgkm) ----
        #pragma unroll
        for (int g = 0; g < 2; g++) {
            bf16x8 pa = *(const bf16x8*)(Prow + (((g*4 + quad) ^ swz) << 3));
            #pragma unroll
            for (int ct = 0; ct < 4; ct++) {
                bf16x8 vbf = *(const bf16x8*)(Vl + (ct*2 + g)*512 + lane*8);
                o[ct] = __builtin_amdgcn_mfma_f32_16x16x32_bf16(pa, vbf, o[ct], 0, 0, 0);
            }
        }

        __syncthreads();
    }

    // ---- final l reduction (over quads) + epilogue ----
    lsum += __shfl_xor(lsum, 16);
    lsum += __shfl_xor(lsum, 32);
    float inv = 1.0f / lsum;               // per lane, q = l16
    float i0 = __shfl(inv, quad*4 + 0);
    float i1 = __shfl(inv, quad*4 + 1);
    float i2 = __shfl(inv, quad*4 + 2);
    float i3 = __shfl(inv, quad*4 + 3);
    #pragma unroll
    for (int ct = 0; ct < 4; ct++) {
        int col = h * HD + ct*16 + l16;
        long rb = (long)(b * SEQ + q0 + w*16 + quad*4);
        ctx[(rb + 0) * DIM + col] = f2bf(o[ct][0] * i0);
        ctx[(rb + 1) * DIM + col] = f2bf(o[ct][1] * i1);
        ctx[(rb + 2) * DIM + col] = f2bf(o[ct][2] * i2);
        ctx[(rb + 3) * DIM + col] = f2bf(o[ct][3] * i3);
    }
}

// ---------------- output projection (m97 structure, fp32 out) ---------------
__global__ __launch_bounds__(256, 3) void gemm_proj(
    const u16* __restrict__ A, const u16* __restrict__ Bt,
    float* __restrict__ Out)
{
    __shared__ u16 ldsA[8192];
    __shared__ u16 ldsB[8192];

    int n0 = blockIdx.x * 128;
    int m0 = blockIdx.y * 128;
    int tid = threadIdx.x;
    int w = tid >> 6, lane = tid & 63, quad = lane >> 4, l16 = lane & 15;
    int mo = (w & 1) * 64, no = (w >> 1) * 64;
    int l7 = l16 & 7;

    int sr = lane >> 3, sc = lane & 7, gc = sc ^ sr;
    const u16* gA0 = A  + (long)(m0 + sr) * DIM + gc * 8;
    const u16* gB0 = Bt + (long)(n0 + sr) * DIM + gc * 8;

    floatx4 acc[4][4];
    #pragma unroll
    for (int mt = 0; mt < 4; mt++)
        #pragma unroll
        for (int nt = 0; nt < 4; nt++) acc[mt][nt] = (floatx4){0.f,0.f,0.f,0.f};

    for (int k0 = 0; k0 < DIM; k0 += 64) {
        #pragma unroll
        for (int i = 0; i < 4; i++) {
            int ch = w * 4 + i;
            gload16(gA0 + (long)ch * 8 * DIM + k0, &ldsA[ch * 512]);
            gload16(gB0 + (long)ch * 8 * DIM + k0, &ldsB[ch * 512]);
        }
        __syncthreads();

        #pragma unroll
        for (int kc = 0; kc < 2; kc++) {
            int swz = ((kc * 4 + quad) ^ l7) * 8;
            bf16x8 af[4], bf[4];
            #pragma unroll
            for (int t4 = 0; t4 < 4; t4++) {
                af[t4] = *(const bf16x8*)&ldsA[(mo + t4*16 + l16) * 64 + swz];
                bf[t4] = *(const bf16x8*)&ldsB[(no + t4*16 + l16) * 64 + swz];
            }
            #pragma unroll
            for (int mt = 0; mt < 4; mt++)
                #pragma unroll
                for (int nt = 0; nt < 4; nt++)
                    acc[mt][nt] = __builtin_amdgcn_mfma_f32_16x16x32_bf16(
                        af[mt], bf[nt], acc[mt][nt], 0, 0, 0);
        }
        __syncthreads();
    }

    #pragma unroll
    for (int mt = 0; mt < 4; mt++)
        #pragma unroll
        for (int nt = 0; nt < 4; nt++)
            #pragma unroll
            for (int r = 0; r < 4; r++) {
                int row = m0 + mo + mt*16 + quad*4 + r;
                int col = n0 + no + nt*16 + l16;
                Out[(long)row * DIM + col] = acc[mt][nt][r];
            }
}

extern "C" void kernel_launch(void* const* d_in, const int* in_sizes, int n_in,
                              void* d_out, int out_size, void* d_ws, size_t ws_size,
                              hipStream_t stream) {
    const float* x  = (const float*)d_in[0];
    const float* Wq = (const float*)d_in[1];
    const float* Wk = (const float*)d_in[2];
    const float* Wv = (const float*)d_in[3];
    const float* Wo = (const float*)d_in[4];
    const int* mask = (const int*)d_in[5];
    float* out = (float*)d_out;

    char* ws = (char*)d_ws;
    size_t off = 0;
    u16* xb  = (u16*)(ws + off); off += (size_t)ROWS * DIM * 2;
    u16* wqb = (u16*)(ws + off); off += (size_t)DIM * DIM * 2;   // wq/wk/wv contiguous = Wcat
    u16* wkb = (u16*)(ws + off); off += (size_t)DIM * DIM * 2;
    u16* wvb = (u16*)(ws + off); off += (size_t)DIM * DIM * 2;
    u16* wob = (u16*)(ws + off); off += (size_t)DIM * DIM * 2;
    u16* Qh  = (u16*)(ws + off); off += (size_t)ROWS * DIM * 2;
    u16* Kfr = (u16*)(ws + off); off += (size_t)ROWS * DIM * 2;
    u16* Vfr = (u16*)(ws + off); off += (size_t)ROWS * DIM * 2;
    u16* ctx = (u16*)(ws + off); off += (size_t)ROWS * DIM * 2;
    float* biasf = (float*)(ws + off); off += (size_t)BS * SEQ * 4;

    convert_all<<<5128, 256, 0, stream>>>(x, Wq, Wk, Wv, Wo, mask,
                                          xb, wqb, wkb, wvb, wob, biasf);
    gemm_qkv_fused<<<dim3(12, 64), 256, 0, stream>>>(xb, wqb, Qh, Kfr, Vfr);
    flash_attn<<<BS * HEADS * (SEQ / 64), 256, 0, stream>>>(Qh, Kfr, Vfr, biasf, ctx);
    gemm_proj<<<dim3(4, 64), 256, 0, stream>>>(ctx, wob, out);

    (void)in_sizes; (void)n_in; (void)out_size; (void)ws_size;
}

// Round 6
// 173.454 us; speedup vs baseline: 2.7063x; 1.0061x over previous
//
#include <hip/hip_runtime.h>
#include <hip/hip_bf16.h>

#define BS 4
#define SEQ 2048
#define DIM 512
#define HEADS 8
#define HD 64
#define ROWS (BS*SEQ)   // 8192
// (1/sqrt(64)) * log2(e) folded into K at projection time
#define SCL2E 0.1803368801111244f
#define NEGB (-1.4426950408889634e6f)   // -1e6 * log2(e)

typedef __attribute__((ext_vector_type(8))) short bf16x8;
typedef __attribute__((ext_vector_type(4))) short bf16x4;
typedef __attribute__((ext_vector_type(4))) float floatx4;
typedef unsigned short u16;
typedef unsigned int u32;

#if defined(__has_builtin)
# if __has_builtin(__builtin_amdgcn_mfma_f32_16x16x16bf16_1k)
#  define HAVE_MFMA16 1
# endif
#endif
#ifndef HAVE_MFMA16
# define HAVE_MFMA16 0
#endif

__device__ __forceinline__ u16 f2bf(float f) {
    union { float f; unsigned u; } v; v.f = f;
    unsigned r = v.u + 0x7fff + ((v.u >> 16) & 1);
    return (u16)(r >> 16);
}

__device__ __forceinline__ unsigned pack2bf(float a, float b) {
#if __has_builtin(__builtin_amdgcn_cvt_pk_bf16_f32)
    typedef __attribute__((ext_vector_type(2))) __bf16 bf2;
    union { bf2 v; unsigned u; } cv;
    cv.v = __builtin_amdgcn_cvt_pk_bf16_f32(a, b);
    return cv.u;
#else
    return (unsigned)f2bf(a) | ((unsigned)f2bf(b) << 16);
#endif
}

__device__ __forceinline__ float fexp2(float x) {
#if __has_builtin(__builtin_amdgcn_exp2f)
    return __builtin_amdgcn_exp2f(x);     // raw v_exp_f32
#else
    return __expf(x * 0.6931471805599453f);
#endif
}

// async global->LDS, 16B per lane. g is PER-LANE global addr, l is wave-uniform.
__device__ __forceinline__ void gload16(const u16* g, u16* l) {
    __builtin_amdgcn_global_load_lds(
        (const __attribute__((address_space(1))) u32*)g,
        (__attribute__((address_space(3))) u32*)l, 16, 0, 0);
}

// ---------------- fp32 -> bf16 conversion; mask -> exp2-domain bias ---------
__global__ __launch_bounds__(256) void convert_all(
    const float* __restrict__ x, const float* __restrict__ Wq,
    const float* __restrict__ Wk, const float* __restrict__ Wv,
    const float* __restrict__ Wo, const int* __restrict__ mask,
    u16* __restrict__ xb, u16* __restrict__ wqb,
    u16* __restrict__ wkb, u16* __restrict__ wvb,
    u16* __restrict__ wob, float* __restrict__ biasf)
{
    int i = blockIdx.x * 256 + threadIdx.x;
    if (i < 1048576 + 262144) {
        const float* src; u16* dst; int off;
        if (i < 1048576) { src = x; dst = xb; off = i; }
        else {
            int j = i - 1048576; int seg = j >> 16; off = j & 65535;
            src = seg == 0 ? Wq : seg == 1 ? Wk : seg == 2 ? Wv : Wo;
            dst = seg == 0 ? wqb : seg == 1 ? wkb : seg == 2 ? wvb : wob;
        }
        float4 v = ((const float4*)src)[off];
        ushort4 o;
        o.x = f2bf(v.x); o.y = f2bf(v.y); o.z = f2bf(v.z); o.w = f2bf(v.w);
        ((ushort4*)dst)[off] = o;
    } else {
        int jb = i - 1310720;                      // 0..2047
        int4 mv = ((const int4*)mask)[jb];
        float4 bo;
        bo.x = (mv.x == 1) ? 0.f : NEGB;
        bo.y = (mv.y == 1) ? 0.f : NEGB;
        bo.z = (mv.z == 1) ? 0.f : NEGB;
        bo.w = (mv.w == 1) ? 0.f : NEGB;
        ((float4*)biasf)[jb] = bo;
    }
}

// ---------------- fused QKV GEMM: C = x @ [Wq;Wk;Wv]^T ----------------------
// V epilogue (HAVE_MFMA16): 16x16x16 B-frag chunks:
//   addr = tile + (klo16*4 + ct)*256 + (quad*16 + d15)*4 + j
//   element (key = kt*64 + klo16*16 + quad*4 + j, d = ct*16 + d15)
__global__ __launch_bounds__(256, 3) void gemm_qkv_fused(
    const u16* __restrict__ A, const u16* __restrict__ Wcat,
    u16* __restrict__ Oq, u16* __restrict__ Okf, u16* __restrict__ Ovf)
{
    __shared__ u16 ldsA[8192];   // 128 rows x 64, chunk i (1KB) = rows 8i..8i+7
    __shared__ u16 ldsB[8192];

    int n0 = blockIdx.x * 128;   // 0..1535
    int m0 = blockIdx.y * 128;
    int tid = threadIdx.x;
    int w = tid >> 6, lane = tid & 63, quad = lane >> 4, l16 = lane & 15;
    int mo = (w & 1) * 64, no = (w >> 1) * 64;
    int l7 = l16 & 7;

    int sr = lane >> 3, sc = lane & 7, gc = sc ^ sr;   // staging row/chunk-swz
    const u16* gA0 = A    + (long)(m0 + sr) * DIM + gc * 8;
    const u16* gB0 = Wcat + (long)(n0 + sr) * DIM + gc * 8;

    floatx4 acc[4][4];
    #pragma unroll
    for (int mt = 0; mt < 4; mt++)
        #pragma unroll
        for (int nt = 0; nt < 4; nt++) acc[mt][nt] = (floatx4){0.f,0.f,0.f,0.f};

    for (int k0 = 0; k0 < DIM; k0 += 64) {
        #pragma unroll
        for (int i = 0; i < 4; i++) {
            int ch = w * 4 + i;
            gload16(gA0 + (long)ch * 8 * DIM + k0, &ldsA[ch * 512]);
            gload16(gB0 + (long)ch * 8 * DIM + k0, &ldsB[ch * 512]);
        }
        __syncthreads();

        #pragma unroll
        for (int kc = 0; kc < 2; kc++) {
            int swz = ((kc * 4 + quad) ^ l7) * 8;
            bf16x8 af[4], bf[4];
            #pragma unroll
            for (int t4 = 0; t4 < 4; t4++) {
                af[t4] = *(const bf16x8*)&ldsA[(mo + t4*16 + l16) * 64 + swz];
                bf[t4] = *(const bf16x8*)&ldsB[(no + t4*16 + l16) * 64 + swz];
            }
            #pragma unroll
            for (int mt = 0; mt < 4; mt++)
                #pragma unroll
                for (int nt = 0; nt < 4; nt++)
                    acc[mt][nt] = __builtin_amdgcn_mfma_f32_16x16x32_bf16(
                        af[mt], bf[nt], acc[mt][nt], 0, 0, 0);
        }
        __syncthreads();
    }

    int seg = n0 >> 9;    // block-uniform: 0=Q 1=K 2=V
    if (seg == 0) {
        #pragma unroll
        for (int mt = 0; mt < 4; mt++)
            #pragma unroll
            for (int nt = 0; nt < 4; nt++)
                #pragma unroll
                for (int r = 0; r < 4; r++) {
                    int row = m0 + mo + mt*16 + quad*4 + r;      // b*SEQ+n
                    int col9 = (n0 + no + nt*16 + l16) & 511;    // h*64+d
                    int b = row >> 11, n = row & 2047, h = col9 >> 6, d = col9 & 63;
                    Oq[(((long)(b * HEADS + h) * SEQ + n) << 6) + d] = f2bf(acc[mt][nt][r]);
                }
    } else if (seg == 1) {
        #pragma unroll
        for (int mt = 0; mt < 4; mt++)
            #pragma unroll
            for (int nt = 0; nt < 4; nt++)
                #pragma unroll
                for (int r = 0; r < 4; r++) {
                    int row = m0 + mo + mt*16 + quad*4 + r;
                    int col9 = (n0 + no + nt*16 + l16) & 511;
                    int b = row >> 11, keyn = row & 2047, h = col9 >> 6, dd = col9 & 63;
                    int kt = keyn >> 6, ntk = (keyn >> 4) & 3, l16k = keyn & 15;
                    int g = dd >> 5, quadk = (dd >> 3) & 3, j = dd & 7;
                    long offv = ((long)((b*HEADS + h)*32 + kt) << 12)
                              + ((ntk*2 + g) << 9) + ((quadk*16 + l16k) << 3) + j;
                    Okf[offv] = f2bf(acc[mt][nt][r] * SCL2E);
                }
    } else {
#if HAVE_MFMA16
        // V in 16x16x16 B-frag chunk order
        #pragma unroll
        for (int mt = 0; mt < 4; mt++)
            #pragma unroll
            for (int nt = 0; nt < 4; nt++) {
                int rowb = m0 + mo + mt*16 + quad*4;
                int col9 = (n0 + no + nt*16 + l16) & 511;
                int b = rowb >> 11, keyn = rowb & 2047, h = col9 >> 6, dd = col9 & 63;
                int kt = keyn >> 6;
                int klo16 = mt;                 // (keyn&63)>>4 == mt (mo&63==0)
                int ctv = dd >> 4, d15 = dd & 15;
                long offv = ((long)((b*HEADS + h)*32 + kt) << 12)
                          + ((klo16*4 + ctv) << 8) + ((quad*16 + d15) << 2);
                ushort4 st;
                st.x = f2bf(acc[mt][nt][0]); st.y = f2bf(acc[mt][nt][1]);
                st.z = f2bf(acc[mt][nt][2]); st.w = f2bf(acc[mt][nt][3]);
                *(ushort4*)&Ovf[offv] = st;
            }
#else
        #pragma unroll
        for (int mt = 0; mt < 4; mt++)
            #pragma unroll
            for (int nt = 0; nt < 4; nt++) {
                int rowb = m0 + mo + mt*16 + quad*4;
                int col9 = (n0 + no + nt*16 + l16) & 511;
                int b = rowb >> 11, keyn = rowb & 2047, h = col9 >> 6, dd = col9 & 63;
                int kt = keyn >> 6, g = (keyn >> 5) & 1, quadv = (keyn >> 3) & 3, jk = keyn & 7;
                int ctv = dd >> 4, l16v = dd & 15;
                long offv = ((long)((b*HEADS + h)*32 + kt) << 12)
                          + ((ctv*2 + g) << 9) + ((quadv*16 + l16v) << 3) + jk;
                ushort4 st;
                st.x = f2bf(acc[mt][nt][0]); st.y = f2bf(acc[mt][nt][1]);
                st.z = f2bf(acc[mt][nt][2]); st.w = f2bf(acc[mt][nt][3]);
                *(ushort4*)&Ovf[offv] = st;
            }
#endif
    }
}

#if HAVE_MFMA16
// ---------------- flash attention: key-split, zero-barrier tile loop --------
// Wave w owns keys [16w,16w+16) of each 64-key tile: reads only its 2KB K +
// 2KB V per tile; P passes C-regs -> A-regs directly (16x16x16 PV); partial
// O[64q][64d] per wave reduced across waves once at the end via LDS rotation.
__global__ __launch_bounds__(256, 3) void flash_attn(
    const u16* __restrict__ Q, const u16* __restrict__ Kf,
    const u16* __restrict__ Vf, const float* __restrict__ biasf,
    u16* __restrict__ ctx)
{
    // loop: [0,8192) K dbuf (2x4096), [8192,16384) V dbuf
    // after: floats [0,4096) O slots, floats [4096,4352) lsum
    __shared__ u16 lds[16384];

    int bx = blockIdx.x;
    int q0 = (bx & 31) * 64;
    int h  = (bx >> 5) & 7;
    int b  = bx >> 8;
    int bh = b * HEADS + h;

    int tid = threadIdx.x;
    int w = tid >> 6, lane = tid & 63, quad = lane >> 4, l16 = lane & 15;

    // Q B-frags for all 4 q-tiles (wave needs all 64 q)
    bf16x8 qb[4][2];
    #pragma unroll
    for (int nt = 0; nt < 4; nt++) {
        const u16* qp = Q + ((long)bh * SEQ + q0 + nt*16 + l16) * HD + quad * 8;
        qb[nt][0] = *(const bf16x8*)(qp);
        qb[nt][1] = *(const bf16x8*)(qp + 32);
    }

    const u16* Kbh = Kf + ((long)bh << 17);
    const u16* Vbh = Vf + ((long)bh << 17);
    const float* bb = biasf + b * SEQ + w*16 + quad*4;   // bias indexed by KEY

    u16* K0 = &lds[0];    u16* K1 = &lds[4096];
    u16* V0 = &lds[8192]; u16* V1 = &lds[12288];

    // stage tile 0 (per-wave-private chunks)
    gload16(Kbh + w*1024       + lane*8, K0 + w*1024);
    gload16(Kbh + w*1024 + 512 + lane*8, K0 + w*1024 + 512);
    gload16(Vbh + w*1024       + lane*8, V0 + w*1024);
    gload16(Vbh + w*1024 + 512 + lane*8, V0 + w*1024 + 512);

    floatx4 o[4][4];
    #pragma unroll
    for (int nt = 0; nt < 4; nt++)
        #pragma unroll
        for (int ct = 0; ct < 4; ct++) o[nt][ct] = (floatx4){0.f,0.f,0.f,0.f};
    float ls[4] = {0.f, 0.f, 0.f, 0.f};

    for (int t = 0; t < 32; t++) {
        u16* Kc = (t & 1) ? K1 : K0;
        u16* Vc = (t & 1) ? V1 : V0;
        u16* Kn = (t & 1) ? K0 : K1;
        u16* Vn = (t & 1) ? V0 : V1;

        // drain outstanding LDS-DMA (last tile's prefetch) before reading
        __builtin_amdgcn_s_waitcnt(0x0F70);   // vmcnt(0) only

        // this wave's fragments -> registers
        bf16x8 ka0 = *(const bf16x8*)(Kc + w*1024       + lane*8);
        bf16x8 ka1 = *(const bf16x8*)(Kc + w*1024 + 512 + lane*8);
        bf16x4 vb[4];
        #pragma unroll
        for (int ct = 0; ct < 4; ct++)
            vb[ct] = *(const bf16x4*)(Vc + w*1024 + ct*256 + lane*4);

        // prefetch next tile (async; lands in the other buffer)
        if (t < 31) {
            const u16* kp = Kbh + (long)(t+1)*4096 + w*1024 + lane*8;
            const u16* vp = Vbh + (long)(t+1)*4096 + w*1024 + lane*8;
            gload16(kp,       Kn + w*1024);
            gload16(kp + 512, Kn + w*1024 + 512);
            gload16(vp,       Vn + w*1024);
            gload16(vp + 512, Vn + w*1024 + 512);
        }

        float4 bv = *(const float4*)(bb + t*64);    // bias for this wave's 4 keys

        #pragma unroll
        for (int nt = 0; nt < 4; nt++) {
            // S^T[16key][16q] = K.Q^T + bias (bias rides in as C-init; key=quad*4+r)
            floatx4 s;
            s[0] = bv.x; s[1] = bv.y; s[2] = bv.z; s[3] = bv.w;
            s = __builtin_amdgcn_mfma_f32_16x16x32_bf16(ka0, qb[nt][0], s, 0, 0, 0);
            s = __builtin_amdgcn_mfma_f32_16x16x32_bf16(ka1, qb[nt][1], s, 0, 0, 0);
            float p0 = fexp2(s[0]);
            float p1 = fexp2(s[1]);
            float p2 = fexp2(s[2]);
            float p3 = fexp2(s[3]);
            ls[nt] += (p0 + p1) + (p2 + p3);
            // C layout (q=l16, key=quad*4+r) == A layout (m=l16, k=quad*4+j)
            union { bf16x4 v; unsigned u[2]; } pu;
            pu.u[0] = pack2bf(p0, p1);
            pu.u[1] = pack2bf(p2, p3);
            #pragma unroll
            for (int ct = 0; ct < 4; ct++)
                o[nt][ct] = __builtin_amdgcn_mfma_f32_16x16x16bf16_1k(
                    pu.v, vb[ct], o[nt][ct], 0, 0, 0);
        }
    }

    __syncthreads();    // everyone done with K/V LDS; switch to reduction use
    float* ldsf = (float*)lds;
    floatx4* ldsv = (floatx4*)lds;

    // lsum: reduce over quads (keys within wave), publish per (wave, q)
    #pragma unroll
    for (int nt = 0; nt < 4; nt++) {
        ls[nt] += __shfl_xor(ls[nt], 16);
        ls[nt] += __shfl_xor(ls[nt], 32);
    }
    if (quad == 0) {
        #pragma unroll
        for (int nt = 0; nt < 4; nt++)
            ldsf[4096 + w*64 + nt*16 + l16] = ls[nt];
    }
    __syncthreads();

    // O rotation: 3 rounds; wave w ends owning full O for q-tile nt==w
    #pragma unroll
    for (int i = 1; i < 4; i++) {
        int tslot = (w + i) & 3;          // wave-uniform
        #pragma unroll
        for (int nt = 0; nt < 4; nt++)
            if (nt == tslot) {
                #pragma unroll
                for (int ct = 0; ct < 4; ct++)
                    ldsv[nt*256 + ct*64 + lane] = o[nt][ct];
            }
        __syncthreads();
        #pragma unroll
        for (int nt = 0; nt < 4; nt++)
            if (nt == w) {
                #pragma unroll
                for (int ct = 0; ct < 4; ct++) {
                    floatx4 v = ldsv[nt*256 + ct*64 + lane];
                    o[nt][ct] += v;
                }
            }
        __syncthreads();
    }

    // epilogue: wave w owns q = q0 + w*16 + quad*4 + r; d = ct*16 + l16
    #pragma unroll
    for (int nt = 0; nt < 4; nt++) {
        if (nt != w) continue;            // wave-uniform
        float inv[4];
        #pragma unroll
        for (int r = 0; r < 4; r++) {
            int q = w*16 + quad*4 + r;
            float s = ldsf[4096 + q] + ldsf[4096 + 64 + q]
                    + ldsf[4096 + 128 + q] + ldsf[4096 + 192 + q];
            inv[r] = 1.0f / s;
        }
        #pragma unroll
        for (int ct = 0; ct < 4; ct++) {
            int col = h * HD + ct*16 + l16;
            long rb = (long)(b * SEQ + q0 + w*16 + quad*4);
            #pragma unroll
            for (int r = 0; r < 4; r++)
                ctx[(rb + r) * DIM + col] = f2bf(o[nt][ct][r] * inv[r]);
        }
    }
}
#else
// ---------------- fallback: R5 flash attention ------------------------------
__global__ __launch_bounds__(256, 4) void flash_attn(
    const u16* __restrict__ Q, const u16* __restrict__ Kf,
    const u16* __restrict__ Vf, const float* __restrict__ biasf,
    u16* __restrict__ ctx)
{
    __shared__ u16 lds[20480];

    int bx = blockIdx.x;
    int q0 = (bx & 31) * 64;
    int h  = (bx >> 5) & 7;
    int b  = bx >> 8;
    int bh = b * HEADS + h;

    int tid = threadIdx.x;
    int w = tid >> 6, lane = tid & 63, quad = lane >> 4, l16 = lane & 15;

    const u16* Qp = Q + ((long)bh * SEQ + q0 + w*16 + l16) * HD + quad * 8;
    bf16x8 qb0 = *(const bf16x8*)(Qp);
    bf16x8 qb1 = *(const bf16x8*)(Qp + 32);

    const u16* Kbh = Kf + ((long)bh << 17);
    const u16* Vbh = Vf + ((long)bh << 17);
    const float* bbase = biasf + b * SEQ + quad * 4;

    u16* Prow = &lds[16384 + w * 1024 + l16 * 64];
    int swz = l16 & 7;

    {
        const u16* gk = Kbh + (2*w)*512 + lane*8;
        const u16* gv = Vbh + (2*w)*512 + lane*8;
        gload16(gk,       &lds[(2*w)*512]);
        gload16(gk + 512, &lds[(2*w+1)*512]);
        gload16(gv,       &lds[8192 + (2*w)*512]);
        gload16(gv + 512, &lds[8192 + (2*w+1)*512]);
    }
    __syncthreads();

    floatx4 o[4];
    #pragma unroll
    for (int ct = 0; ct < 4; ct++) o[ct] = (floatx4){0.f, 0.f, 0.f, 0.f};
    float lsum = 0.f;

    for (int t = 0; t < 32; t++) {
        int cur = t & 1;
        if (t < 31) {
            long tb = (long)(t + 1) << 12;
            int nb = cur ^ 1;
            const u16* gk = Kbh + tb + (2*w)*512 + lane*8;
            const u16* gv = Vbh + tb + (2*w)*512 + lane*8;
            gload16(gk,       &lds[nb*4096 + (2*w)*512]);
            gload16(gk + 512, &lds[nb*4096 + (2*w+1)*512]);
            gload16(gv,       &lds[8192 + nb*4096 + (2*w)*512]);
            gload16(gv + 512, &lds[8192 + nb*4096 + (2*w+1)*512]);
        }

        const u16* Kl = &lds[cur * 4096];
        const u16* Vl = &lds[8192 + cur * 4096];

        #pragma unroll
        for (int nt = 0; nt < 4; nt++) {
            float4 bv = *(const float4*)(bbase + t*64 + nt*16);
            bf16x8 ka0 = *(const bf16x8*)(Kl + (nt*2 + 0)*512 + lane*8);
            bf16x8 ka1 = *(const bf16x8*)(Kl + (nt*2 + 1)*512 + lane*8);
            floatx4 tt;
            tt[0] = bv.x; tt[1] = bv.y; tt[2] = bv.z; tt[3] = bv.w;
            tt = __builtin_amdgcn_mfma_f32_16x16x32_bf16(ka0, qb0, tt, 0, 0, 0);
            tt = __builtin_amdgcn_mfma_f32_16x16x32_bf16(ka1, qb1, tt, 0, 0, 0);
            float p0 = fexp2(tt[0]);
            float p1 = fexp2(tt[1]);
            float p2 = fexp2(tt[2]);
            float p3 = fexp2(tt[3]);
            lsum += (p0 + p1) + (p2 + p3);
            int gx = nt*2 + (quad >> 1);
            uint2 pu;
            pu.x = pack2bf(p0, p1);
            pu.y = pack2bf(p2, p3);
            *(uint2*)(Prow + ((gx ^ swz) << 3) + (quad & 1)*4) = pu;
        }

        #pragma unroll
        for (int g = 0; g < 2; g++) {
            bf16x8 pa = *(const bf16x8*)(Prow + (((g*4 + quad) ^ swz) << 3));
            #pragma unroll
            for (int ct = 0; ct < 4; ct++) {
                bf16x8 vbf = *(const bf16x8*)(Vl + (ct*2 + g)*512 + lane*8);
                o[ct] = __builtin_amdgcn_mfma_f32_16x16x32_bf16(pa, vbf, o[ct], 0, 0, 0);
            }
        }

        __syncthreads();
    }

    lsum += __shfl_xor(lsum, 16);
    lsum += __shfl_xor(lsum, 32);
    float inv = 1.0f / lsum;
    float i0 = __shfl(inv, quad*4 + 0);
    float i1 = __shfl(inv, quad*4 + 1);
    float i2 = __shfl(inv, quad*4 + 2);
    float i3 = __shfl(inv, quad*4 + 3);
    #pragma unroll
    for (int ct = 0; ct < 4; ct++) {
        int col = h * HD + ct*16 + l16;
        long rb = (long)(b * SEQ + q0 + w*16 + quad*4);
        ctx[(rb + 0) * DIM + col] = f2bf(o[ct][0] * i0);
        ctx[(rb + 1) * DIM + col] = f2bf(o[ct][1] * i1);
        ctx[(rb + 2) * DIM + col] = f2bf(o[ct][2] * i2);
        ctx[(rb + 3) * DIM + col] = f2bf(o[ct][3] * i3);
    }
}
#endif

// ---------------- output projection (m97 structure, fp32 out) ---------------
__global__ __launch_bounds__(256, 3) void gemm_proj(
    const u16* __restrict__ A, const u16* __restrict__ Bt,
    float* __restrict__ Out)
{
    __shared__ u16 ldsA[8192];
    __shared__ u16 ldsB[8192];

    int n0 = blockIdx.x * 128;
    int m0 = blockIdx.y * 128;
    int tid = threadIdx.x;
    int w = tid >> 6, lane = tid & 63, quad = lane >> 4, l16 = lane & 15;
    int mo = (w & 1) * 64, no = (w >> 1) * 64;
    int l7 = l16 & 7;

    int sr = lane >> 3, sc = lane & 7, gc = sc ^ sr;
    const u16* gA0 = A  + (long)(m0 + sr) * DIM + gc * 8;
    const u16* gB0 = Bt + (long)(n0 + sr) * DIM + gc * 8;

    floatx4 acc[4][4];
    #pragma unroll
    for (int mt = 0; mt < 4; mt++)
        #pragma unroll
        for (int nt = 0; nt < 4; nt++) acc[mt][nt] = (floatx4){0.f,0.f,0.f,0.f};

    for (int k0 = 0; k0 < DIM; k0 += 64) {
        #pragma unroll
        for (int i = 0; i < 4; i++) {
            int ch = w * 4 + i;
            gload16(gA0 + (long)ch * 8 * DIM + k0, &ldsA[ch * 512]);
            gload16(gB0 + (long)ch * 8 * DIM + k0, &ldsB[ch * 512]);
        }
        __syncthreads();

        #pragma unroll
        for (int kc = 0; kc < 2; kc++) {
            int swz = ((kc * 4 + quad) ^ l7) * 8;
            bf16x8 af[4], bf[4];
            #pragma unroll
            for (int t4 = 0; t4 < 4; t4++) {
                af[t4] = *(const bf16x8*)&ldsA[(mo + t4*16 + l16) * 64 + swz];
                bf[t4] = *(const bf16x8*)&ldsB[(no + t4*16 + l16) * 64 + swz];
            }
            #pragma unroll
            for (int mt = 0; mt < 4; mt++)
                #pragma unroll
                for (int nt = 0; nt < 4; nt++)
                    acc[mt][nt] = __builtin_amdgcn_mfma_f32_16x16x32_bf16(
                        af[mt], bf[nt], acc[mt][nt], 0, 0, 0);
        }
        __syncthreads();
    }

    #pragma unroll
    for (int mt = 0; mt < 4; mt++)
        #pragma unroll
        for (int nt = 0; nt < 4; nt++)
            #pragma unroll
            for (int r = 0; r < 4; r++) {
                int row = m0 + mo + mt*16 + quad*4 + r;
                int col = n0 + no + nt*16 + l16;
                Out[(long)row * DIM + col] = acc[mt][nt][r];
            }
}

extern "C" void kernel_launch(void* const* d_in, const int* in_sizes, int n_in,
                              void* d_out, int out_size, void* d_ws, size_t ws_size,
                              hipStream_t stream) {
    const float* x  = (const float*)d_in[0];
    const float* Wq = (const float*)d_in[1];
    const float* Wk = (const float*)d_in[2];
    const float* Wv = (const float*)d_in[3];
    const float* Wo = (const float*)d_in[4];
    const int* mask = (const int*)d_in[5];
    float* out = (float*)d_out;

    char* ws = (char*)d_ws;
    size_t off = 0;
    u16* xb  = (u16*)(ws + off); off += (size_t)ROWS * DIM * 2;
    u16* wqb = (u16*)(ws + off); off += (size_t)DIM * DIM * 2;   // wq/wk/wv contiguous = Wcat
    u16* wkb = (u16*)(ws + off); off += (size_t)DIM * DIM * 2;
    u16* wvb = (u16*)(ws + off); off += (size_t)DIM * DIM * 2;
    u16* wob = (u16*)(ws + off); off += (size_t)DIM * DIM * 2;
    u16* Qh  = (u16*)(ws + off); off += (size_t)ROWS * DIM * 2;
    u16* Kfr = (u16*)(ws + off); off += (size_t)ROWS * DIM * 2;
    u16* Vfr = (u16*)(ws + off); off += (size_t)ROWS * DIM * 2;
    u16* ctx = (u16*)(ws + off); off += (size_t)ROWS * DIM * 2;
    float* biasf = (float*)(ws + off); off += (size_t)BS * SEQ * 4;

    convert_all<<<5128, 256, 0, stream>>>(x, Wq, Wk, Wv, Wo, mask,
                                          xb, wqb, wkb, wvb, wob, biasf);
    gemm_qkv_fused<<<dim3(12, 64), 256, 0, stream>>>(xb, wqb, Qh, Kfr, Vfr);
    flash_attn<<<BS * HEADS * (SEQ / 64), 256, 0, stream>>>(Qh, Kfr, Vfr, biasf, ctx);
    gemm_proj<<<dim3(4, 64), 256, 0, stream>>>(ctx, wob, out);

    (void)in_sizes; (void)n_in; (void)out_size; (void)ws_size;
}

// Round 7
// 164.310 us; speedup vs baseline: 2.8569x; 1.0557x over previous
//
#include <hip/hip_runtime.h>
#include <hip/hip_bf16.h>

#define BS 4
#define SEQ 2048
#define DIM 512
#define HEADS 8
#define HD 64
#define ROWS (BS*SEQ)   // 8192
// (1/sqrt(64)) * log2(e) folded into K at projection time
#define SCL2E 0.1803368801111244f
#define NEGB (-1.4426950408889634e6f)   // -1e6 * log2(e)

typedef __attribute__((ext_vector_type(8))) short bf16x8;
typedef __attribute__((ext_vector_type(4))) short bf16x4;
typedef __attribute__((ext_vector_type(4))) float floatx4;
typedef unsigned short u16;
typedef unsigned int u32;

#if defined(__has_builtin)
# if __has_builtin(__builtin_amdgcn_mfma_f32_16x16x16bf16_1k)
#  define HAVE_MFMA16 1
# endif
#endif
#ifndef HAVE_MFMA16
# define HAVE_MFMA16 0
#endif

__device__ __forceinline__ u16 f2bf(float f) {
    union { float f; unsigned u; } v; v.f = f;
    unsigned r = v.u + 0x7fff + ((v.u >> 16) & 1);
    return (u16)(r >> 16);
}

__device__ __forceinline__ unsigned pack2bf(float a, float b) {
#if __has_builtin(__builtin_amdgcn_cvt_pk_bf16_f32)
    typedef __attribute__((ext_vector_type(2))) __bf16 bf2;
    union { bf2 v; unsigned u; } cv;
    cv.v = __builtin_amdgcn_cvt_pk_bf16_f32(a, b);
    return cv.u;
#else
    return (unsigned)f2bf(a) | ((unsigned)f2bf(b) << 16);
#endif
}

__device__ __forceinline__ float fexp2(float x) {
#if __has_builtin(__builtin_amdgcn_exp2f)
    return __builtin_amdgcn_exp2f(x);     // raw v_exp_f32
#else
    return __expf(x * 0.6931471805599453f);
#endif
}

// async global->LDS, 16B per lane. g is PER-LANE global addr, l is wave-uniform.
__device__ __forceinline__ void gload16(const u16* g, u16* l) {
    __builtin_amdgcn_global_load_lds(
        (const __attribute__((address_space(1))) u32*)g,
        (__attribute__((address_space(3))) u32*)l, 16, 0, 0);
}

// ---------------- fp32 -> bf16 conversion; mask -> exp2-domain bias ---------
__global__ __launch_bounds__(256) void convert_all(
    const float* __restrict__ x, const float* __restrict__ Wq,
    const float* __restrict__ Wk, const float* __restrict__ Wv,
    const float* __restrict__ Wo, const int* __restrict__ mask,
    u16* __restrict__ xb, u16* __restrict__ wqb,
    u16* __restrict__ wkb, u16* __restrict__ wvb,
    u16* __restrict__ wob, float* __restrict__ biasf)
{
    int i = blockIdx.x * 256 + threadIdx.x;
    if (i < 1048576 + 262144) {
        const float* src; u16* dst; int off;
        if (i < 1048576) { src = x; dst = xb; off = i; }
        else {
            int j = i - 1048576; int seg = j >> 16; off = j & 65535;
            src = seg == 0 ? Wq : seg == 1 ? Wk : seg == 2 ? Wv : Wo;
            dst = seg == 0 ? wqb : seg == 1 ? wkb : seg == 2 ? wvb : wob;
        }
        float4 v = ((const float4*)src)[off];
        ushort4 o;
        o.x = f2bf(v.x); o.y = f2bf(v.y); o.z = f2bf(v.z); o.w = f2bf(v.w);
        ((ushort4*)dst)[off] = o;
    } else {
        int jb = i - 1310720;                      // 0..2047
        int4 mv = ((const int4*)mask)[jb];
        float4 bo;
        bo.x = (mv.x == 1) ? 0.f : NEGB;
        bo.y = (mv.y == 1) ? 0.f : NEGB;
        bo.z = (mv.z == 1) ? 0.f : NEGB;
        bo.w = (mv.w == 1) ? 0.f : NEGB;
        ((float4*)biasf)[jb] = bo;
    }
}

// ---------------- fused QKV GEMM: C = x @ [Wq;Wk;Wv]^T ----------------------
// V epilogue (HAVE_MFMA16): per-lane 32B chunks for direct reg loads in flash:
//   off = tile*4096 + wf*1024 + (quadf*16 + l16f)*16 + ct*4 + j
//   element (key = t*64 + wf*16 + quadf*4 + j, d = ct*16 + l16f)
__global__ __launch_bounds__(256, 3) void gemm_qkv_fused(
    const u16* __restrict__ A, const u16* __restrict__ Wcat,
    u16* __restrict__ Oq, u16* __restrict__ Okf, u16* __restrict__ Ovf)
{
    __shared__ u16 ldsA[8192];   // 128 rows x 64, chunk i (1KB) = rows 8i..8i+7
    __shared__ u16 ldsB[8192];

    int n0 = blockIdx.x * 128;   // 0..1535
    int m0 = blockIdx.y * 128;
    int tid = threadIdx.x;
    int w = tid >> 6, lane = tid & 63, quad = lane >> 4, l16 = lane & 15;
    int mo = (w & 1) * 64, no = (w >> 1) * 64;
    int l7 = l16 & 7;

    int sr = lane >> 3, sc = lane & 7, gc = sc ^ sr;   // staging row/chunk-swz
    const u16* gA0 = A    + (long)(m0 + sr) * DIM + gc * 8;
    const u16* gB0 = Wcat + (long)(n0 + sr) * DIM + gc * 8;

    floatx4 acc[4][4];
    #pragma unroll
    for (int mt = 0; mt < 4; mt++)
        #pragma unroll
        for (int nt = 0; nt < 4; nt++) acc[mt][nt] = (floatx4){0.f,0.f,0.f,0.f};

    for (int k0 = 0; k0 < DIM; k0 += 64) {
        #pragma unroll
        for (int i = 0; i < 4; i++) {
            int ch = w * 4 + i;
            gload16(gA0 + (long)ch * 8 * DIM + k0, &ldsA[ch * 512]);
            gload16(gB0 + (long)ch * 8 * DIM + k0, &ldsB[ch * 512]);
        }
        __syncthreads();

        #pragma unroll
        for (int kc = 0; kc < 2; kc++) {
            int swz = ((kc * 4 + quad) ^ l7) * 8;
            bf16x8 af[4], bf[4];
            #pragma unroll
            for (int t4 = 0; t4 < 4; t4++) {
                af[t4] = *(const bf16x8*)&ldsA[(mo + t4*16 + l16) * 64 + swz];
                bf[t4] = *(const bf16x8*)&ldsB[(no + t4*16 + l16) * 64 + swz];
            }
            #pragma unroll
            for (int mt = 0; mt < 4; mt++)
                #pragma unroll
                for (int nt = 0; nt < 4; nt++)
                    acc[mt][nt] = __builtin_amdgcn_mfma_f32_16x16x32_bf16(
                        af[mt], bf[nt], acc[mt][nt], 0, 0, 0);
        }
        __syncthreads();
    }

    int seg = n0 >> 9;    // block-uniform: 0=Q 1=K 2=V
    if (seg == 0) {
        #pragma unroll
        for (int mt = 0; mt < 4; mt++)
            #pragma unroll
            for (int nt = 0; nt < 4; nt++)
                #pragma unroll
                for (int r = 0; r < 4; r++) {
                    int row = m0 + mo + mt*16 + quad*4 + r;      // b*SEQ+n
                    int col9 = (n0 + no + nt*16 + l16) & 511;    // h*64+d
                    int b = row >> 11, n = row & 2047, h = col9 >> 6, d = col9 & 63;
                    Oq[(((long)(b * HEADS + h) * SEQ + n) << 6) + d] = f2bf(acc[mt][nt][r]);
                }
    } else if (seg == 1) {
        #pragma unroll
        for (int mt = 0; mt < 4; mt++)
            #pragma unroll
            for (int nt = 0; nt < 4; nt++)
                #pragma unroll
                for (int r = 0; r < 4; r++) {
                    int row = m0 + mo + mt*16 + quad*4 + r;
                    int col9 = (n0 + no + nt*16 + l16) & 511;
                    int b = row >> 11, keyn = row & 2047, h = col9 >> 6, dd = col9 & 63;
                    int kt = keyn >> 6, ntk = (keyn >> 4) & 3, l16k = keyn & 15;
                    int g = dd >> 5, quadk = (dd >> 3) & 3, j = dd & 7;
                    long offv = ((long)((b*HEADS + h)*32 + kt) << 12)
                              + ((ntk*2 + g) << 9) + ((quadk*16 + l16k) << 3) + j;
                    Okf[offv] = f2bf(acc[mt][nt][r] * SCL2E);
                }
    } else {
#if HAVE_MFMA16
        // V in per-lane-32B order (see header comment)
        #pragma unroll
        for (int mt = 0; mt < 4; mt++)
            #pragma unroll
            for (int nt = 0; nt < 4; nt++) {
                int rowb = m0 + mo + mt*16 + quad*4;
                int col9 = (n0 + no + nt*16 + l16) & 511;
                int b = rowb >> 11, keyn = rowb & 2047, h = col9 >> 6, dd = col9 & 63;
                int kt = keyn >> 6;
                int wf = (keyn >> 4) & 3, quadf = (keyn >> 2) & 3;   // j = r
                int ctf = dd >> 4, l16f = dd & 15;
                long offv = ((long)((b*HEADS + h)*32 + kt) << 12)
                          + (wf << 10) + ((quadf*16 + l16f) << 4) + (ctf << 2);
                ushort4 st;
                st.x = f2bf(acc[mt][nt][0]); st.y = f2bf(acc[mt][nt][1]);
                st.z = f2bf(acc[mt][nt][2]); st.w = f2bf(acc[mt][nt][3]);
                *(ushort4*)&Ovf[offv] = st;
            }
#else
        #pragma unroll
        for (int mt = 0; mt < 4; mt++)
            #pragma unroll
            for (int nt = 0; nt < 4; nt++) {
                int rowb = m0 + mo + mt*16 + quad*4;
                int col9 = (n0 + no + nt*16 + l16) & 511;
                int b = rowb >> 11, keyn = rowb & 2047, h = col9 >> 6, dd = col9 & 63;
                int kt = keyn >> 6, g = (keyn >> 5) & 1, quadv = (keyn >> 3) & 3, jk = keyn & 7;
                int ctv = dd >> 4, l16v = dd & 15;
                long offv = ((long)((b*HEADS + h)*32 + kt) << 12)
                          + ((ctv*2 + g) << 9) + ((quadv*16 + l16v) << 3) + jk;
                ushort4 st;
                st.x = f2bf(acc[mt][nt][0]); st.y = f2bf(acc[mt][nt][1]);
                st.z = f2bf(acc[mt][nt][2]); st.w = f2bf(acc[mt][nt][3]);
                *(ushort4*)&Ovf[offv] = st;
            }
#endif
    }
}

#if HAVE_MFMA16
// ---------------- flash attention: key-split, register-direct, no LDS loop --
// Wave w owns keys [16w,16w+16) of each 64-key tile. K/V fragment layouts are
// lane-contiguous in global memory -> coalesced global_load_dwordx4 straight
// to registers (no LDS, no barriers, no hard vmcnt(0) in the loop); depth-1
// rolling prefetch. LDS used only for the final O / lsum cross-wave reduction.
__global__ __launch_bounds__(256, 3) void flash_attn(
    const u16* __restrict__ Q, const u16* __restrict__ Kf,
    const u16* __restrict__ Vf, const float* __restrict__ biasf,
    u16* __restrict__ ctx)
{
    __shared__ float red[4352];   // [0,4096) O slots (1024 floatx4), [4096,4352) lsum

    int bx = blockIdx.x;
    int q0 = (bx & 31) * 64;
    int h  = (bx >> 5) & 7;
    int b  = bx >> 8;
    int bh = b * HEADS + h;

    int tid = threadIdx.x;
    int w = tid >> 6, lane = tid & 63, quad = lane >> 4, l16 = lane & 15;

    // Q B-frags for all 4 q-tiles (wave needs all 64 q)
    bf16x8 qb[4][2];
    #pragma unroll
    for (int nt = 0; nt < 4; nt++) {
        const u16* qp = Q + ((long)bh * SEQ + q0 + nt*16 + l16) * HD + quad * 8;
        qb[nt][0] = *(const bf16x8*)(qp);
        qb[nt][1] = *(const bf16x8*)(qp + 32);
    }

    const u16* Kbh = Kf + ((long)bh << 17) + w*1024 + lane*8;    // + t*4096
    const u16* Vbh = Vf + ((long)bh << 17) + w*1024 + lane*16;   // + t*4096
    const float* bb = biasf + b * SEQ + w*16 + quad*4;           // + t*64

    // rolling preload: tile 0
    bf16x8 ka0 = *(const bf16x8*)(Kbh);
    bf16x8 ka1 = *(const bf16x8*)(Kbh + 512);
    bf16x8 vlo = *(const bf16x8*)(Vbh);
    bf16x8 vhi = *(const bf16x8*)(Vbh + 8);
    float4 bv  = *(const float4*)(bb);

    floatx4 o[4][4];
    #pragma unroll
    for (int nt = 0; nt < 4; nt++)
        #pragma unroll
        for (int ct = 0; ct < 4; ct++) o[nt][ct] = (floatx4){0.f,0.f,0.f,0.f};
    float ls[4] = {0.f, 0.f, 0.f, 0.f};

    #pragma unroll 2
    for (int t = 0; t < 32; t++) {
        // prefetch next tile into fresh registers (compiler emits vmcnt(N))
        bf16x8 ka0n = ka0, ka1n = ka1, vlon = vlo, vhin = vhi;
        float4 bvn = bv;
        if (t < 31) {
            const u16* kp = Kbh + (long)(t+1)*4096;
            const u16* vp = Vbh + (long)(t+1)*4096;
            ka0n = *(const bf16x8*)(kp);
            ka1n = *(const bf16x8*)(kp + 512);
            vlon = *(const bf16x8*)(vp);
            vhin = *(const bf16x8*)(vp + 8);
            bvn  = *(const float4*)(bb + (t+1)*64);
        }

        union { bf16x8 v8; bf16x4 v4[2]; } uvl, uvh;
        uvl.v8 = vlo; uvh.v8 = vhi;
        bf16x4 vb[4] = { uvl.v4[0], uvl.v4[1], uvh.v4[0], uvh.v4[1] };

        #pragma unroll
        for (int nt = 0; nt < 4; nt++) {
            // S^T[16key][16q] = K.Q^T + bias (C-init; key=quad*4+r, q=l16)
            floatx4 s;
            s[0] = bv.x; s[1] = bv.y; s[2] = bv.z; s[3] = bv.w;
            s = __builtin_amdgcn_mfma_f32_16x16x32_bf16(ka0, qb[nt][0], s, 0, 0, 0);
            s = __builtin_amdgcn_mfma_f32_16x16x32_bf16(ka1, qb[nt][1], s, 0, 0, 0);
            float p0 = fexp2(s[0]);
            float p1 = fexp2(s[1]);
            float p2 = fexp2(s[2]);
            float p3 = fexp2(s[3]);
            ls[nt] += (p0 + p1) + (p2 + p3);
            // C layout (q=l16, key=quad*4+r) == 16x16x16 A layout (m=l16, k=quad*4+j)
            union { bf16x4 v; unsigned u[2]; } pu;
            pu.u[0] = pack2bf(p0, p1);
            pu.u[1] = pack2bf(p2, p3);
            #pragma unroll
            for (int ct = 0; ct < 4; ct++)
                o[nt][ct] = __builtin_amdgcn_mfma_f32_16x16x16bf16_1k(
                    pu.v, vb[ct], o[nt][ct], 0, 0, 0);
        }

        ka0 = ka0n; ka1 = ka1n; vlo = vlon; vhi = vhin; bv = bvn;
    }

    __syncthreads();
    float* ldsf = red;
    floatx4* ldsv = (floatx4*)red;

    // lsum: reduce over quads (keys within wave), publish per (wave, q)
    #pragma unroll
    for (int nt = 0; nt < 4; nt++) {
        ls[nt] += __shfl_xor(ls[nt], 16);
        ls[nt] += __shfl_xor(ls[nt], 32);
    }
    if (quad == 0) {
        #pragma unroll
        for (int nt = 0; nt < 4; nt++)
            ldsf[4096 + w*64 + nt*16 + l16] = ls[nt];
    }
    __syncthreads();

    // O rotation: 3 rounds; wave w ends owning full O for q-tile nt==w
    #pragma unroll
    for (int i = 1; i < 4; i++) {
        int tslot = (w + i) & 3;          // wave-uniform
        #pragma unroll
        for (int nt = 0; nt < 4; nt++)
            if (nt == tslot) {
                #pragma unroll
                for (int ct = 0; ct < 4; ct++)
                    ldsv[nt*256 + ct*64 + lane] = o[nt][ct];
            }
        __syncthreads();
        #pragma unroll
        for (int nt = 0; nt < 4; nt++)
            if (nt == w) {
                #pragma unroll
                for (int ct = 0; ct < 4; ct++) {
                    floatx4 v = ldsv[nt*256 + ct*64 + lane];
                    o[nt][ct] += v;
                }
            }
        __syncthreads();
    }

    // epilogue: wave w owns q = q0 + w*16 + quad*4 + r; d = ct*16 + l16
    #pragma unroll
    for (int nt = 0; nt < 4; nt++) {
        if (nt != w) continue;            // wave-uniform
        float inv[4];
        #pragma unroll
        for (int r = 0; r < 4; r++) {
            int q = w*16 + quad*4 + r;
            float s = ldsf[4096 + q] + ldsf[4096 + 64 + q]
                    + ldsf[4096 + 128 + q] + ldsf[4096 + 192 + q];
            inv[r] = 1.0f / s;
        }
        #pragma unroll
        for (int ct = 0; ct < 4; ct++) {
            int col = h * HD + ct*16 + l16;
            long rb = (long)(b * SEQ + q0 + w*16 + quad*4);
            #pragma unroll
            for (int r = 0; r < 4; r++)
                ctx[(rb + r) * DIM + col] = f2bf(o[nt][ct][r] * inv[r]);
        }
    }
}
#else
// ---------------- fallback: R5 flash attention ------------------------------
__global__ __launch_bounds__(256, 4) void flash_attn(
    const u16* __restrict__ Q, const u16* __restrict__ Kf,
    const u16* __restrict__ Vf, const float* __restrict__ biasf,
    u16* __restrict__ ctx)
{
    __shared__ u16 lds[20480];

    int bx = blockIdx.x;
    int q0 = (bx & 31) * 64;
    int h  = (bx >> 5) & 7;
    int b  = bx >> 8;
    int bh = b * HEADS + h;

    int tid = threadIdx.x;
    int w = tid >> 6, lane = tid & 63, quad = lane >> 4, l16 = lane & 15;

    const u16* Qp = Q + ((long)bh * SEQ + q0 + w*16 + l16) * HD + quad * 8;
    bf16x8 qb0 = *(const bf16x8*)(Qp);
    bf16x8 qb1 = *(const bf16x8*)(Qp + 32);

    const u16* Kbh = Kf + ((long)bh << 17);
    const u16* Vbh = Vf + ((long)bh << 17);
    const float* bbase = biasf + b * SEQ + quad * 4;

    u16* Prow = &lds[16384 + w * 1024 + l16 * 64];
    int swz = l16 & 7;

    {
        const u16* gk = Kbh + (2*w)*512 + lane*8;
        const u16* gv = Vbh + (2*w)*512 + lane*8;
        gload16(gk,       &lds[(2*w)*512]);
        gload16(gk + 512, &lds[(2*w+1)*512]);
        gload16(gv,       &lds[8192 + (2*w)*512]);
        gload16(gv + 512, &lds[8192 + (2*w+1)*512]);
    }
    __syncthreads();

    floatx4 o[4];
    #pragma unroll
    for (int ct = 0; ct < 4; ct++) o[ct] = (floatx4){0.f, 0.f, 0.f, 0.f};
    float lsum = 0.f;

    for (int t = 0; t < 32; t++) {
        int cur = t & 1;
        if (t < 31) {
            long tb = (long)(t + 1) << 12;
            int nb = cur ^ 1;
            const u16* gk = Kbh + tb + (2*w)*512 + lane*8;
            const u16* gv = Vbh + tb + (2*w)*512 + lane*8;
            gload16(gk,       &lds[nb*4096 + (2*w)*512]);
            gload16(gk + 512, &lds[nb*4096 + (2*w+1)*512]);
            gload16(gv,       &lds[8192 + nb*4096 + (2*w)*512]);
            gload16(gv + 512, &lds[8192 + nb*4096 + (2*w+1)*512]);
        }

        const u16* Kl = &lds[cur * 4096];
        const u16* Vl = &lds[8192 + cur * 4096];

        #pragma unroll
        for (int nt = 0; nt < 4; nt++) {
            float4 bv = *(const float4*)(bbase + t*64 + nt*16);
            bf16x8 ka0 = *(const bf16x8*)(Kl + (nt*2 + 0)*512 + lane*8);
            bf16x8 ka1 = *(const bf16x8*)(Kl + (nt*2 + 1)*512 + lane*8);
            floatx4 tt;
            tt[0] = bv.x; tt[1] = bv.y; tt[2] = bv.z; tt[3] = bv.w;
            tt = __builtin_amdgcn_mfma_f32_16x16x32_bf16(ka0, qb0, tt, 0, 0, 0);
            tt = __builtin_amdgcn_mfma_f32_16x16x32_bf16(ka1, qb1, tt, 0, 0, 0);
            float p0 = fexp2(tt[0]);
            float p1 = fexp2(tt[1]);
            float p2 = fexp2(tt[2]);
            float p3 = fexp2(tt[3]);
            lsum += (p0 + p1) + (p2 + p3);
            int gx = nt*2 + (quad >> 1);
            uint2 pu;
            pu.x = pack2bf(p0, p1);
            pu.y = pack2bf(p2, p3);
            *(uint2*)(Prow + ((gx ^ swz) << 3) + (quad & 1)*4) = pu;
        }

        #pragma unroll
        for (int g = 0; g < 2; g++) {
            bf16x8 pa = *(const bf16x8*)(Prow + (((g*4 + quad) ^ swz) << 3));
            #pragma unroll
            for (int ct = 0; ct < 4; ct++) {
                bf16x8 vbf = *(const bf16x8*)(Vl + (ct*2 + g)*512 + lane*8);
                o[ct] = __builtin_amdgcn_mfma_f32_16x16x32_bf16(pa, vbf, o[ct], 0, 0, 0);
            }
        }

        __syncthreads();
    }

    lsum += __shfl_xor(lsum, 16);
    lsum += __shfl_xor(lsum, 32);
    float inv = 1.0f / lsum;
    float i0 = __shfl(inv, quad*4 + 0);
    float i1 = __shfl(inv, quad*4 + 1);
    float i2 = __shfl(inv, quad*4 + 2);
    float i3 = __shfl(inv, quad*4 + 3);
    #pragma unroll
    for (int ct = 0; ct < 4; ct++) {
        int col = h * HD + ct*16 + l16;
        long rb = (long)(b * SEQ + q0 + w*16 + quad*4);
        ctx[(rb + 0) * DIM + col] = f2bf(o[ct][0] * i0);
        ctx[(rb + 1) * DIM + col] = f2bf(o[ct][1] * i1);
        ctx[(rb + 2) * DIM + col] = f2bf(o[ct][2] * i2);
        ctx[(rb + 3) * DIM + col] = f2bf(o[ct][3] * i3);
    }
}
#endif

// ---------------- output projection: 64x128 tile, 512 blocks (2/CU) ---------
__global__ __launch_bounds__(256, 4) void gemm_proj(
    const u16* __restrict__ A, const u16* __restrict__ Bt,
    float* __restrict__ Out)
{
    __shared__ u16 ldsA[4096];   // 64 x 64
    __shared__ u16 ldsB[8192];   // 128 x 64

    int n0 = blockIdx.x * 128;
    int m0 = blockIdx.y * 64;
    int tid = threadIdx.x;
    int w = tid >> 6, lane = tid & 63, quad = lane >> 4, l16 = lane & 15;
    int l7 = l16 & 7;

    int sr = lane >> 3, sc = lane & 7, gc = sc ^ sr;
    const u16* gA0 = A  + (long)(m0 + sr) * DIM + gc * 8;
    const u16* gB0 = Bt + (long)(n0 + sr) * DIM + gc * 8;

    floatx4 acc[8];
    #pragma unroll
    for (int nt = 0; nt < 8; nt++) acc[nt] = (floatx4){0.f,0.f,0.f,0.f};

    for (int k0 = 0; k0 < DIM; k0 += 64) {
        gload16(gA0 + (long)(2*w)   * 8 * DIM + k0, &ldsA[(2*w)   * 512]);
        gload16(gA0 + (long)(2*w+1) * 8 * DIM + k0, &ldsA[(2*w+1) * 512]);
        #pragma unroll
        for (int i = 0; i < 4; i++)
            gload16(gB0 + (long)(4*w+i) * 8 * DIM + k0, &ldsB[(4*w+i) * 512]);
        __syncthreads();

        #pragma unroll
        for (int kc = 0; kc < 2; kc++) {
            int swz = ((kc * 4 + quad) ^ l7) * 8;
            bf16x8 af = *(const bf16x8*)&ldsA[(w*16 + l16) * 64 + swz];
            #pragma unroll
            for (int nt = 0; nt < 8; nt++) {
                bf16x8 bfv = *(const bf16x8*)&ldsB[(nt*16 + l16) * 64 + swz];
                acc[nt] = __builtin_amdgcn_mfma_f32_16x16x32_bf16(
                    af, bfv, acc[nt], 0, 0, 0);
            }
        }
        __syncthreads();
    }

    #pragma unroll
    for (int nt = 0; nt < 8; nt++)
        #pragma unroll
        for (int r = 0; r < 4; r++) {
            int row = m0 + w*16 + quad*4 + r;
            int col = n0 + nt*16 + l16;
            Out[(long)row * DIM + col] = acc[nt][r];
        }
}

extern "C" void kernel_launch(void* const* d_in, const int* in_sizes, int n_in,
                              void* d_out, int out_size, void* d_ws, size_t ws_size,
                              hipStream_t stream) {
    const float* x  = (const float*)d_in[0];
    const float* Wq = (const float*)d_in[1];
    const float* Wk = (const float*)d_in[2];
    const float* Wv = (const float*)d_in[3];
    const float* Wo = (const float*)d_in[4];
    const int* mask = (const int*)d_in[5];
    float* out = (float*)d_out;

    char* ws = (char*)d_ws;
    size_t off = 0;
    u16* xb  = (u16*)(ws + off); off += (size_t)ROWS * DIM * 2;
    u16* wqb = (u16*)(ws + off); off += (size_t)DIM * DIM * 2;   // wq/wk/wv contiguous = Wcat
    u16* wkb = (u16*)(ws + off); off += (size_t)DIM * DIM * 2;
    u16* wvb = (u16*)(ws + off); off += (size_t)DIM * DIM * 2;
    u16* wob = (u16*)(ws + off); off += (size_t)DIM * DIM * 2;
    u16* Qh  = (u16*)(ws + off); off += (size_t)ROWS * DIM * 2;
    u16* Kfr = (u16*)(ws + off); off += (size_t)ROWS * DIM * 2;
    u16* Vfr = (u16*)(ws + off); off += (size_t)ROWS * DIM * 2;
    u16* ctx = (u16*)(ws + off); off += (size_t)ROWS * DIM * 2;
    float* biasf = (float*)(ws + off); off += (size_t)BS * SEQ * 4;

    convert_all<<<5128, 256, 0, stream>>>(x, Wq, Wk, Wv, Wo, mask,
                                          xb, wqb, wkb, wvb, wob, biasf);
    gemm_qkv_fused<<<dim3(12, 64), 256, 0, stream>>>(xb, wqb, Qh, Kfr, Vfr);
    flash_attn<<<BS * HEADS * (SEQ / 64), 256, 0, stream>>>(Qh, Kfr, Vfr, biasf, ctx);
    gemm_proj<<<dim3(4, 128), 256, 0, stream>>>(ctx, wob, out);

    (void)in_sizes; (void)n_in; (void)out_size; (void)ws_size;
}

// Round 8
// 156.623 us; speedup vs baseline: 2.9971x; 1.0491x over previous
//
#include <hip/hip_runtime.h>
#include <hip/hip_bf16.h>

#define BS 4
#define SEQ 2048
#define DIM 512
#define HEADS 8
#define HD 64
#define ROWS (BS*SEQ)   // 8192
// (1/sqrt(64)) * log2(e) folded into K at projection time
#define SCL2E 0.1803368801111244f
#define NEGB (-1.4426950408889634e6f)   // -1e6 * log2(e)

typedef __attribute__((ext_vector_type(8))) short bf16x8;
typedef __attribute__((ext_vector_type(4))) short bf16x4;
typedef __attribute__((ext_vector_type(4))) float floatx4;
typedef unsigned short u16;
typedef unsigned int u32;

#if defined(__has_builtin)
# if __has_builtin(__builtin_amdgcn_mfma_f32_16x16x16bf16_1k)
#  define HAVE_MFMA16 1
# endif
#endif
#ifndef HAVE_MFMA16
# define HAVE_MFMA16 0
#endif

__device__ __forceinline__ u16 f2bf(float f) {
    union { float f; unsigned u; } v; v.f = f;
    unsigned r = v.u + 0x7fff + ((v.u >> 16) & 1);
    return (u16)(r >> 16);
}

__device__ __forceinline__ unsigned pack2bf(float a, float b) {
#if __has_builtin(__builtin_amdgcn_cvt_pk_bf16_f32)
    typedef __attribute__((ext_vector_type(2))) __bf16 bf2;
    union { bf2 v; unsigned u; } cv;
    cv.v = __builtin_amdgcn_cvt_pk_bf16_f32(a, b);
    return cv.u;
#else
    return (unsigned)f2bf(a) | ((unsigned)f2bf(b) << 16);
#endif
}

__device__ __forceinline__ float fexp2(float x) {
#if __has_builtin(__builtin_amdgcn_exp2f)
    return __builtin_amdgcn_exp2f(x);     // raw v_exp_f32
#else
    return __expf(x * 0.6931471805599453f);
#endif
}

// async global->LDS, 16B per lane. g is PER-LANE global addr, l is wave-uniform.
__device__ __forceinline__ void gload16(const u16* g, u16* l) {
    __builtin_amdgcn_global_load_lds(
        (const __attribute__((address_space(1))) u32*)g,
        (__attribute__((address_space(3))) u32*)l, 16, 0, 0);
}

// ---------------- fp32 -> bf16 conversion; mask -> exp2-domain bias ---------
__global__ __launch_bounds__(256) void convert_all(
    const float* __restrict__ x, const float* __restrict__ Wq,
    const float* __restrict__ Wk, const float* __restrict__ Wv,
    const float* __restrict__ Wo, const int* __restrict__ mask,
    u16* __restrict__ xb, u16* __restrict__ wqb,
    u16* __restrict__ wkb, u16* __restrict__ wvb,
    u16* __restrict__ wob, float* __restrict__ biasf)
{
    int i = blockIdx.x * 256 + threadIdx.x;
    if (i < 1048576 + 262144) {
        const float* src; u16* dst; int off;
        if (i < 1048576) { src = x; dst = xb; off = i; }
        else {
            int j = i - 1048576; int seg = j >> 16; off = j & 65535;
            src = seg == 0 ? Wq : seg == 1 ? Wk : seg == 2 ? Wv : Wo;
            dst = seg == 0 ? wqb : seg == 1 ? wkb : seg == 2 ? wvb : wob;
        }
        float4 v = ((const float4*)src)[off];
        ushort4 o;
        o.x = f2bf(v.x); o.y = f2bf(v.y); o.z = f2bf(v.z); o.w = f2bf(v.w);
        ((ushort4*)dst)[off] = o;
    } else {
        int jb = i - 1310720;                      // 0..2047
        int4 mv = ((const int4*)mask)[jb];
        float4 bo;
        bo.x = (mv.x == 1) ? 0.f : NEGB;
        bo.y = (mv.y == 1) ? 0.f : NEGB;
        bo.z = (mv.z == 1) ? 0.f : NEGB;
        bo.w = (mv.w == 1) ? 0.f : NEGB;
        ((float4*)biasf)[jb] = bo;
    }
}

// ---------------- fused QKV GEMM: C = x @ [Wq;Wk;Wv]^T ----------------------
// V epilogue (HAVE_MFMA16): per-lane 32B chunks for direct reg loads in flash:
//   off = tile*4096 + wf*1024 + (quadf*16 + l16f)*16 + ct*4 + j
//   element (key = t*64 + wf*16 + quadf*4 + j, d = ct*16 + l16f)
__global__ __launch_bounds__(256, 3) void gemm_qkv_fused(
    const u16* __restrict__ A, const u16* __restrict__ Wcat,
    u16* __restrict__ Oq, u16* __restrict__ Okf, u16* __restrict__ Ovf)
{
    __shared__ u16 ldsA[8192];   // 128 rows x 64, chunk i (1KB) = rows 8i..8i+7
    __shared__ u16 ldsB[8192];

    int n0 = blockIdx.x * 128;   // 0..1535
    int m0 = blockIdx.y * 128;
    int tid = threadIdx.x;
    int w = tid >> 6, lane = tid & 63, quad = lane >> 4, l16 = lane & 15;
    int mo = (w & 1) * 64, no = (w >> 1) * 64;
    int l7 = l16 & 7;

    int sr = lane >> 3, sc = lane & 7, gc = sc ^ sr;   // staging row/chunk-swz
    const u16* gA0 = A    + (long)(m0 + sr) * DIM + gc * 8;
    const u16* gB0 = Wcat + (long)(n0 + sr) * DIM + gc * 8;

    floatx4 acc[4][4];
    #pragma unroll
    for (int mt = 0; mt < 4; mt++)
        #pragma unroll
        for (int nt = 0; nt < 4; nt++) acc[mt][nt] = (floatx4){0.f,0.f,0.f,0.f};

    for (int k0 = 0; k0 < DIM; k0 += 64) {
        #pragma unroll
        for (int i = 0; i < 4; i++) {
            int ch = w * 4 + i;
            gload16(gA0 + (long)ch * 8 * DIM + k0, &ldsA[ch * 512]);
            gload16(gB0 + (long)ch * 8 * DIM + k0, &ldsB[ch * 512]);
        }
        __syncthreads();

        #pragma unroll
        for (int kc = 0; kc < 2; kc++) {
            int swz = ((kc * 4 + quad) ^ l7) * 8;
            bf16x8 af[4], bf[4];
            #pragma unroll
            for (int t4 = 0; t4 < 4; t4++) {
                af[t4] = *(const bf16x8*)&ldsA[(mo + t4*16 + l16) * 64 + swz];
                bf[t4] = *(const bf16x8*)&ldsB[(no + t4*16 + l16) * 64 + swz];
            }
            #pragma unroll
            for (int mt = 0; mt < 4; mt++)
                #pragma unroll
                for (int nt = 0; nt < 4; nt++)
                    acc[mt][nt] = __builtin_amdgcn_mfma_f32_16x16x32_bf16(
                        af[mt], bf[nt], acc[mt][nt], 0, 0, 0);
        }
        __syncthreads();
    }

    int seg = n0 >> 9;    // block-uniform: 0=Q 1=K 2=V
    if (seg == 0) {
        #pragma unroll
        for (int mt = 0; mt < 4; mt++)
            #pragma unroll
            for (int nt = 0; nt < 4; nt++)
                #pragma unroll
                for (int r = 0; r < 4; r++) {
                    int row = m0 + mo + mt*16 + quad*4 + r;      // b*SEQ+n
                    int col9 = (n0 + no + nt*16 + l16) & 511;    // h*64+d
                    int b = row >> 11, n = row & 2047, h = col9 >> 6, d = col9 & 63;
                    Oq[(((long)(b * HEADS + h) * SEQ + n) << 6) + d] = f2bf(acc[mt][nt][r]);
                }
    } else if (seg == 1) {
        #pragma unroll
        for (int mt = 0; mt < 4; mt++)
            #pragma unroll
            for (int nt = 0; nt < 4; nt++)
                #pragma unroll
                for (int r = 0; r < 4; r++) {
                    int row = m0 + mo + mt*16 + quad*4 + r;
                    int col9 = (n0 + no + nt*16 + l16) & 511;
                    int b = row >> 11, keyn = row & 2047, h = col9 >> 6, dd = col9 & 63;
                    int kt = keyn >> 6, ntk = (keyn >> 4) & 3, l16k = keyn & 15;
                    int g = dd >> 5, quadk = (dd >> 3) & 3, j = dd & 7;
                    long offv = ((long)((b*HEADS + h)*32 + kt) << 12)
                              + ((ntk*2 + g) << 9) + ((quadk*16 + l16k) << 3) + j;
                    Okf[offv] = f2bf(acc[mt][nt][r] * SCL2E);
                }
    } else {
#if HAVE_MFMA16
        // V in per-lane-32B order (see header comment)
        #pragma unroll
        for (int mt = 0; mt < 4; mt++)
            #pragma unroll
            for (int nt = 0; nt < 4; nt++) {
                int rowb = m0 + mo + mt*16 + quad*4;
                int col9 = (n0 + no + nt*16 + l16) & 511;
                int b = rowb >> 11, keyn = rowb & 2047, h = col9 >> 6, dd = col9 & 63;
                int kt = keyn >> 6;
                int wf = (keyn >> 4) & 3, quadf = (keyn >> 2) & 3;   // j = r
                int ctf = dd >> 4, l16f = dd & 15;
                long offv = ((long)((b*HEADS + h)*32 + kt) << 12)
                          + (wf << 10) + ((quadf*16 + l16f) << 4) + (ctf << 2);
                ushort4 st;
                st.x = f2bf(acc[mt][nt][0]); st.y = f2bf(acc[mt][nt][1]);
                st.z = f2bf(acc[mt][nt][2]); st.w = f2bf(acc[mt][nt][3]);
                *(ushort4*)&Ovf[offv] = st;
            }
#else
        #pragma unroll
        for (int mt = 0; mt < 4; mt++)
            #pragma unroll
            for (int nt = 0; nt < 4; nt++) {
                int rowb = m0 + mo + mt*16 + quad*4;
                int col9 = (n0 + no + nt*16 + l16) & 511;
                int b = rowb >> 11, keyn = rowb & 2047, h = col9 >> 6, dd = col9 & 63;
                int kt = keyn >> 6, g = (keyn >> 5) & 1, quadv = (keyn >> 3) & 3, jk = keyn & 7;
                int ctv = dd >> 4, l16v = dd & 15;
                long offv = ((long)((b*HEADS + h)*32 + kt) << 12)
                          + ((ctv*2 + g) << 9) + ((quadv*16 + l16v) << 3) + jk;
                ushort4 st;
                st.x = f2bf(acc[mt][nt][0]); st.y = f2bf(acc[mt][nt][1]);
                st.z = f2bf(acc[mt][nt][2]); st.w = f2bf(acc[mt][nt][3]);
                *(ushort4*)&Ovf[offv] = st;
            }
#endif
    }
}

#if HAVE_MFMA16
// ---------------- flash attention: key-split, register-direct ---------------
// XCD swizzle: all 32 q-blocks of one (b,h) land on the same XCD (bx%8
// heuristic) so its 512KB K/V stays in that XCD's 4MB L2.
// lsum accumulated on the MATRIX pipe: o5[nt] = mfma(P, ones_col) with the
// ones column nonzero only at n==0 -> lanes l16==0 hold per-q partial sums.
__global__ __launch_bounds__(256, 3) void flash_attn(
    const u16* __restrict__ Q, const u16* __restrict__ Kf,
    const u16* __restrict__ Vf, const float* __restrict__ biasf,
    u16* __restrict__ ctx)
{
    __shared__ float red[4352];   // [0,4096) O slots (1024 floatx4), [4096,4352) lsum

    int bx = blockIdx.x;
    // decode XCD swizzle: bx = (g&7) + 8*((g>>3)*32 + i), g = b*8+h, i = q-block
    int c  = bx & 7, s = bx >> 3;
    int g  = ((s >> 5) << 3) | c;
    int i  = s & 31;
    int q0 = i * 64;
    int h  = g & 7;
    int b  = g >> 3;
    int bh = b * HEADS + h;

    int tid = threadIdx.x;
    int w = tid >> 6, lane = tid & 63, quad = lane >> 4, l16 = lane & 15;

    // Q B-frags for all 4 q-tiles (wave needs all 64 q)
    bf16x8 qb[4][2];
    #pragma unroll
    for (int nt = 0; nt < 4; nt++) {
        const u16* qp = Q + ((long)bh * SEQ + q0 + nt*16 + l16) * HD + quad * 8;
        qb[nt][0] = *(const bf16x8*)(qp);
        qb[nt][1] = *(const bf16x8*)(qp + 32);
    }

    const u16* Kbh = Kf + ((long)bh << 17) + w*1024 + lane*8;    // + t*4096
    const u16* Vbh = Vf + ((long)bh << 17) + w*1024 + lane*16;   // + t*4096
    const float* bb = biasf + b * SEQ + w*16 + quad*4;           // + t*64

    // ones-column B operand: 1.0 only for n == 0 (lanes l16==0), all k
    short one_s = (l16 == 0) ? (short)0x3F80 : (short)0;
    bf16x4 onesb = { one_s, one_s, one_s, one_s };

    // rolling preload: tile 0
    bf16x8 ka0 = *(const bf16x8*)(Kbh);
    bf16x8 ka1 = *(const bf16x8*)(Kbh + 512);
    bf16x8 vlo = *(const bf16x8*)(Vbh);
    bf16x8 vhi = *(const bf16x8*)(Vbh + 8);
    float4 bv  = *(const float4*)(bb);

    floatx4 o[4][4];
    floatx4 o5[4];
    #pragma unroll
    for (int nt = 0; nt < 4; nt++) {
        #pragma unroll
        for (int ct = 0; ct < 4; ct++) o[nt][ct] = (floatx4){0.f,0.f,0.f,0.f};
        o5[nt] = (floatx4){0.f,0.f,0.f,0.f};
    }

    #pragma unroll 2
    for (int t = 0; t < 32; t++) {
        // prefetch next tile into fresh registers (compiler emits vmcnt(N))
        bf16x8 ka0n = ka0, ka1n = ka1, vlon = vlo, vhin = vhi;
        float4 bvn = bv;
        if (t < 31) {
            const u16* kp = Kbh + (long)(t+1)*4096;
            const u16* vp = Vbh + (long)(t+1)*4096;
            ka0n = *(const bf16x8*)(kp);
            ka1n = *(const bf16x8*)(kp + 512);
            vlon = *(const bf16x8*)(vp);
            vhin = *(const bf16x8*)(vp + 8);
            bvn  = *(const float4*)(bb + (t+1)*64);
        }

        union { bf16x8 v8; bf16x4 v4[2]; } uvl, uvh;
        uvl.v8 = vlo; uvh.v8 = vhi;
        bf16x4 vb[4] = { uvl.v4[0], uvl.v4[1], uvh.v4[0], uvh.v4[1] };

        #pragma unroll
        for (int nt = 0; nt < 4; nt++) {
            // S^T[16key][16q] = K.Q^T + bias (C-init; key=quad*4+r, q=l16)
            floatx4 s2;
            s2[0] = bv.x; s2[1] = bv.y; s2[2] = bv.z; s2[3] = bv.w;
            s2 = __builtin_amdgcn_mfma_f32_16x16x32_bf16(ka0, qb[nt][0], s2, 0, 0, 0);
            s2 = __builtin_amdgcn_mfma_f32_16x16x32_bf16(ka1, qb[nt][1], s2, 0, 0, 0);
            float p0 = fexp2(s2[0]);
            float p1 = fexp2(s2[1]);
            float p2 = fexp2(s2[2]);
            float p3 = fexp2(s2[3]);
            // C layout (q=l16, key=quad*4+r) == 16x16x16 A layout (m=l16, k=quad*4+j)
            union { bf16x4 v; unsigned u[2]; } pu;
            pu.u[0] = pack2bf(p0, p1);
            pu.u[1] = pack2bf(p2, p3);
            #pragma unroll
            for (int ct = 0; ct < 4; ct++)
                o[nt][ct] = __builtin_amdgcn_mfma_f32_16x16x16bf16_1k(
                    pu.v, vb[ct], o[nt][ct], 0, 0, 0);
            // denominator on the matrix pipe (rows q=quad*4+r at col l16==0)
            o5[nt] = __builtin_amdgcn_mfma_f32_16x16x16bf16_1k(
                pu.v, onesb, o5[nt], 0, 0, 0);
        }

        ka0 = ka0n; ka1 = ka1n; vlo = vlon; vhi = vhin; bv = bvn;
    }

    __syncthreads();
    float* ldsf = red;
    floatx4* ldsv = (floatx4*)red;

    // publish per-(wave, q) partial denominators from lanes l16==0
    if (l16 == 0) {
        #pragma unroll
        for (int nt = 0; nt < 4; nt++)
            #pragma unroll
            for (int r = 0; r < 4; r++)
                ldsf[4096 + w*64 + nt*16 + quad*4 + r] = o5[nt][r];
    }
    __syncthreads();

    // O rotation: 3 rounds; wave w ends owning full O for q-tile nt==w
    #pragma unroll
    for (int i2 = 1; i2 < 4; i2++) {
        int tslot = (w + i2) & 3;          // wave-uniform
        #pragma unroll
        for (int nt = 0; nt < 4; nt++)
            if (nt == tslot) {
                #pragma unroll
                for (int ct = 0; ct < 4; ct++)
                    ldsv[nt*256 + ct*64 + lane] = o[nt][ct];
            }
        __syncthreads();
        #pragma unroll
        for (int nt = 0; nt < 4; nt++)
            if (nt == w) {
                #pragma unroll
                for (int ct = 0; ct < 4; ct++) {
                    floatx4 v = ldsv[nt*256 + ct*64 + lane];
                    o[nt][ct] += v;
                }
            }
        __syncthreads();
    }

    // epilogue: wave w owns q = q0 + w*16 + quad*4 + r; d = ct*16 + l16
    #pragma unroll
    for (int nt = 0; nt < 4; nt++) {
        if (nt != w) continue;            // wave-uniform
        float inv[4];
        #pragma unroll
        for (int r = 0; r < 4; r++) {
            int q = w*16 + quad*4 + r;
            float sden = ldsf[4096 + q] + ldsf[4096 + 64 + q]
                       + ldsf[4096 + 128 + q] + ldsf[4096 + 192 + q];
            inv[r] = 1.0f / sden;
        }
        #pragma unroll
        for (int ct = 0; ct < 4; ct++) {
            int col = h * HD + ct*16 + l16;
            long rb = (long)(b * SEQ + q0 + w*16 + quad*4);
            #pragma unroll
            for (int r = 0; r < 4; r++)
                ctx[(rb + r) * DIM + col] = f2bf(o[nt][ct][r] * inv[r]);
        }
    }
}
#else
// ---------------- fallback: R5 flash attention ------------------------------
__global__ __launch_bounds__(256, 4) void flash_attn(
    const u16* __restrict__ Q, const u16* __restrict__ Kf,
    const u16* __restrict__ Vf, const float* __restrict__ biasf,
    u16* __restrict__ ctx)
{
    __shared__ u16 lds[20480];

    int bx = blockIdx.x;
    int q0 = (bx & 31) * 64;
    int h  = (bx >> 5) & 7;
    int b  = bx >> 8;
    int bh = b * HEADS + h;

    int tid = threadIdx.x;
    int w = tid >> 6, lane = tid & 63, quad = lane >> 4, l16 = lane & 15;

    const u16* Qp = Q + ((long)bh * SEQ + q0 + w*16 + l16) * HD + quad * 8;
    bf16x8 qb0 = *(const bf16x8*)(Qp);
    bf16x8 qb1 = *(const bf16x8*)(Qp + 32);

    const u16* Kbh = Kf + ((long)bh << 17);
    const u16* Vbh = Vf + ((long)bh << 17);
    const float* bbase = biasf + b * SEQ + quad * 4;

    u16* Prow = &lds[16384 + w * 1024 + l16 * 64];
    int swz = l16 & 7;

    {
        const u16* gk = Kbh + (2*w)*512 + lane*8;
        const u16* gv = Vbh + (2*w)*512 + lane*8;
        gload16(gk,       &lds[(2*w)*512]);
        gload16(gk + 512, &lds[(2*w+1)*512]);
        gload16(gv,       &lds[8192 + (2*w)*512]);
        gload16(gv + 512, &lds[8192 + (2*w+1)*512]);
    }
    __syncthreads();

    floatx4 o[4];
    #pragma unroll
    for (int ct = 0; ct < 4; ct++) o[ct] = (floatx4){0.f, 0.f, 0.f, 0.f};
    float lsum = 0.f;

    for (int t = 0; t < 32; t++) {
        int cur = t & 1;
        if (t < 31) {
            long tb = (long)(t + 1) << 12;
            int nb = cur ^ 1;
            const u16* gk = Kbh + tb + (2*w)*512 + lane*8;
            const u16* gv = Vbh + tb + (2*w)*512 + lane*8;
            gload16(gk,       &lds[nb*4096 + (2*w)*512]);
            gload16(gk + 512, &lds[nb*4096 + (2*w+1)*512]);
            gload16(gv,       &lds[8192 + nb*4096 + (2*w)*512]);
            gload16(gv + 512, &lds[8192 + nb*4096 + (2*w+1)*512]);
        }

        const u16* Kl = &lds[cur * 4096];
        const u16* Vl = &lds[8192 + cur * 4096];

        #pragma unroll
        for (int nt = 0; nt < 4; nt++) {
            float4 bv = *(const float4*)(bbase + t*64 + nt*16);
            bf16x8 ka0 = *(const bf16x8*)(Kl + (nt*2 + 0)*512 + lane*8);
            bf16x8 ka1 = *(const bf16x8*)(Kl + (nt*2 + 1)*512 + lane*8);
            floatx4 tt;
            tt[0] = bv.x; tt[1] = bv.y; tt[2] = bv.z; tt[3] = bv.w;
            tt = __builtin_amdgcn_mfma_f32_16x16x32_bf16(ka0, qb0, tt, 0, 0, 0);
            tt = __builtin_amdgcn_mfma_f32_16x16x32_bf16(ka1, qb1, tt, 0, 0, 0);
            float p0 = fexp2(tt[0]);
            float p1 = fexp2(tt[1]);
            float p2 = fexp2(tt[2]);
            float p3 = fexp2(tt[3]);
            lsum += (p0 + p1) + (p2 + p3);
            int gx = nt*2 + (quad >> 1);
            uint2 pu;
            pu.x = pack2bf(p0, p1);
            pu.y = pack2bf(p2, p3);
            *(uint2*)(Prow + ((gx ^ swz) << 3) + (quad & 1)*4) = pu;
        }

        #pragma unroll
        for (int g = 0; g < 2; g++) {
            bf16x8 pa = *(const bf16x8*)(Prow + (((g*4 + quad) ^ swz) << 3));
            #pragma unroll
            for (int ct = 0; ct < 4; ct++) {
                bf16x8 vbf = *(const bf16x8*)(Vl + (ct*2 + g)*512 + lane*8);
                o[ct] = __builtin_amdgcn_mfma_f32_16x16x32_bf16(pa, vbf, o[ct], 0, 0, 0);
            }
        }

        __syncthreads();
    }

    lsum += __shfl_xor(lsum, 16);
    lsum += __shfl_xor(lsum, 32);
    float inv = 1.0f / lsum;
    float i0 = __shfl(inv, quad*4 + 0);
    float i1 = __shfl(inv, quad*4 + 1);
    float i2 = __shfl(inv, quad*4 + 2);
    float i3 = __shfl(inv, quad*4 + 3);
    #pragma unroll
    for (int ct = 0; ct < 4; ct++) {
        int col = h * HD + ct*16 + l16;
        long rb = (long)(b * SEQ + q0 + w*16 + quad*4);
        ctx[(rb + 0) * DIM + col] = f2bf(o[ct][0] * i0);
        ctx[(rb + 1) * DIM + col] = f2bf(o[ct][1] * i1);
        ctx[(rb + 2) * DIM + col] = f2bf(o[ct][2] * i2);
        ctx[(rb + 3) * DIM + col] = f2bf(o[ct][3] * i3);
    }
}
#endif

// ---------------- output projection: 64x128 tile, 512 blocks (2/CU) ---------
__global__ __launch_bounds__(256, 4) void gemm_proj(
    const u16* __restrict__ A, const u16* __restrict__ Bt,
    float* __restrict__ Out)
{
    __shared__ u16 ldsA[4096];   // 64 x 64
    __shared__ u16 ldsB[8192];   // 128 x 64

    int n0 = blockIdx.x * 128;
    int m0 = blockIdx.y * 64;
    int tid = threadIdx.x;
    int w = tid >> 6, lane = tid & 63, quad = lane >> 4, l16 = lane & 15;
    int l7 = l16 & 7;

    int sr = lane >> 3, sc = lane & 7, gc = sc ^ sr;
    const u16* gA0 = A  + (long)(m0 + sr) * DIM + gc * 8;
    const u16* gB0 = Bt + (long)(n0 + sr) * DIM + gc * 8;

    floatx4 acc[8];
    #pragma unroll
    for (int nt = 0; nt < 8; nt++) acc[nt] = (floatx4){0.f,0.f,0.f,0.f};

    for (int k0 = 0; k0 < DIM; k0 += 64) {
        gload16(gA0 + (long)(2*w)   * 8 * DIM + k0, &ldsA[(2*w)   * 512]);
        gload16(gA0 + (long)(2*w+1) * 8 * DIM + k0, &ldsA[(2*w+1) * 512]);
        #pragma unroll
        for (int i = 0; i < 4; i++)
            gload16(gB0 + (long)(4*w+i) * 8 * DIM + k0, &ldsB[(4*w+i) * 512]);
        __syncthreads();

        #pragma unroll
        for (int kc = 0; kc < 2; kc++) {
            int swz = ((kc * 4 + quad) ^ l7) * 8;
            bf16x8 af = *(const bf16x8*)&ldsA[(w*16 + l16) * 64 + swz];
            #pragma unroll
            for (int nt = 0; nt < 8; nt++) {
                bf16x8 bfv = *(const bf16x8*)&ldsB[(nt*16 + l16) * 64 + swz];
                acc[nt] = __builtin_amdgcn_mfma_f32_16x16x32_bf16(
                    af, bfv, acc[nt], 0, 0, 0);
            }
        }
        __syncthreads();
    }

    #pragma unroll
    for (int nt = 0; nt < 8; nt++)
        #pragma unroll
        for (int r = 0; r < 4; r++) {
            int row = m0 + w*16 + quad*4 + r;
            int col = n0 + nt*16 + l16;
            Out[(long)row * DIM + col] = acc[nt][r];
        }
}

extern "C" void kernel_launch(void* const* d_in, const int* in_sizes, int n_in,
                              void* d_out, int out_size, void* d_ws, size_t ws_size,
                              hipStream_t stream) {
    const float* x  = (const float*)d_in[0];
    const float* Wq = (const float*)d_in[1];
    const float* Wk = (const float*)d_in[2];
    const float* Wv = (const float*)d_in[3];
    const float* Wo = (const float*)d_in[4];
    const int* mask = (const int*)d_in[5];
    float* out = (float*)d_out;

    char* ws = (char*)d_ws;
    size_t off = 0;
    u16* xb  = (u16*)(ws + off); off += (size_t)ROWS * DIM * 2;
    u16* wqb = (u16*)(ws + off); off += (size_t)DIM * DIM * 2;   // wq/wk/wv contiguous = Wcat
    u16* wkb = (u16*)(ws + off); off += (size_t)DIM * DIM * 2;
    u16* wvb = (u16*)(ws + off); off += (size_t)DIM * DIM * 2;
    u16* wob = (u16*)(ws + off); off += (size_t)DIM * DIM * 2;
    u16* Qh  = (u16*)(ws + off); off += (size_t)ROWS * DIM * 2;
    u16* Kfr = (u16*)(ws + off); off += (size_t)ROWS * DIM * 2;
    u16* Vfr = (u16*)(ws + off); off += (size_t)ROWS * DIM * 2;
    u16* ctx = (u16*)(ws + off); off += (size_t)ROWS * DIM * 2;
    float* biasf = (float*)(ws + off); off += (size_t)BS * SEQ * 4;

    convert_all<<<5128, 256, 0, stream>>>(x, Wq, Wk, Wv, Wo, mask,
                                          xb, wqb, wkb, wvb, wob, biasf);
    gemm_qkv_fused<<<dim3(12, 64), 256, 0, stream>>>(xb, wqb, Qh, Kfr, Vfr);
    flash_attn<<<BS * HEADS * (SEQ / 64), 256, 0, stream>>>(Qh, Kfr, Vfr, biasf, ctx);
    gemm_proj<<<dim3(4, 128), 256, 0, stream>>>(ctx, wob, out);

    (void)in_sizes; (void)n_in; (void)out_size; (void)ws_size;
}